// Round 1
// baseline (403.482 us; speedup 1.0000x reference)
//
#include <hip/hip_runtime.h>

// ---------------------------------------------------------------------------
// DynamicFeaturePyramid forward, MI355X.
// Shapes: x1 (8,32,64,64), x2 (8,32,32,32), x3 (8,32,16,16), x4 (8,32,8,8)
// gf = concat(x1, up(x2), up(x3), up(x4)) -> (8,128,4096)   [never materialized]
// attention: B=8, S=4096, D=64 single head; flash-fused, bf16 MFMA.
// Workspace layout (bytes):
//   Q   (b,i,c) bf16  :        0 .. 4194304
//   K   (b,j,c) bf16  :  4194304 .. 8388608
//   Vt  (b,c,j) bf16  :  8388608 .. 12582912
//   O   (b,i,c) fp32  : 12582912 .. 20971520
//   SW  (b,c,i) fp32  : 20971520 .. 37748736
//   WT1 (c,192) fp32  : 37748736 .. 37847040   (qkv weights transposed; q part *log2e)
//   bqkv(192)   fp32  : 37847040 .. +768 (pad to 37848064)
//   g1wT(c,32)  fp32  : 37848064 .. 37864448
//   g2wT(c,128) fp32  : 37864448 .. 37880832
// Total ~38 MB.
// ---------------------------------------------------------------------------

typedef __attribute__((ext_vector_type(8))) short s16x8;   // 8 bf16 = 4 VGPRs
typedef __attribute__((ext_vector_type(4))) float f32x4;   // MFMA C/D frag

#define LOG2E 1.44269504088896340736f

__device__ __forceinline__ unsigned int f2bf(float f) {
    unsigned int u = __float_as_uint(f);
    u += 0x7fffu + ((u >> 16) & 1u);   // RNE (inputs finite)
    return u >> 16;
}

// ---------------------------------------------------------------------------
// K0: weight prep (transpose + log2e fold). ~33K elements, trivial.
// ---------------------------------------------------------------------------
__global__ __launch_bounds__(256) void k_prep(
    const float* __restrict__ qw, const float* __restrict__ qb,
    const float* __restrict__ kw, const float* __restrict__ kb,
    const float* __restrict__ vw, const float* __restrict__ vb,
    const float* __restrict__ g1w, const float* __restrict__ g2w,
    float* __restrict__ WT1, float* __restrict__ bqkv,
    float* __restrict__ g1wT, float* __restrict__ g2wT) {
  int t = blockIdx.x * 256 + threadIdx.x;
  if (t < 128 * 192) {            // WT1[c][oc], oc in [q64|k64|v64]
    int c = t / 192, oc = t % 192;
    float v;
    if (oc < 64)       v = qw[oc * 128 + c] * LOG2E;
    else if (oc < 128) v = kw[(oc - 64) * 128 + c];
    else               v = vw[(oc - 128) * 128 + c];
    WT1[t] = v;
  }
  if (t < 192) {
    float v;
    if (t < 64)       v = qb[t] * LOG2E;
    else if (t < 128) v = kb[t - 64];
    else              v = vb[t - 128];
    bqkv[t] = v;
  }
  if (t < 128 * 32) { int c = t >> 5, oc = t & 31;  g1wT[t] = g1w[oc * 128 + c]; }
  if (t < 32 * 128) { int c = t >> 7, oc = t & 127; g2wT[t] = g2w[oc * 32 + c]; }
}

// ---------------------------------------------------------------------------
// K1: fused (bilinear-upsample + concat) -> gf tile in LDS -> QKV projection.
// Block: 256 thr handles (b, 64 consecutive positions). Grid 8*64 = 512.
// gf tile: 128 ch x 64 pos, LDS stride 68 (conflict-free staging writes).
// All 64 positions of a block share the same output row oy (i0 % 64 == 0),
// and c = t>>1 makes the x1/x2/x3/x4 branch wave-uniform.
// ---------------------------------------------------------------------------
__global__ __launch_bounds__(256) void k_qkv(
    const float* __restrict__ x1, const float* __restrict__ x2,
    const float* __restrict__ x3, const float* __restrict__ x4,
    const float* __restrict__ WT1, const float* __restrict__ bqkv,
    unsigned short* __restrict__ Qg, unsigned short* __restrict__ Kg,
    unsigned short* __restrict__ Vg) {
  __shared__ float gft[128 * 68];
  const int b = blockIdx.x >> 6;
  const int i0 = (blockIdx.x & 63) << 6;
  const int t = threadIdx.x;
  const int c = t >> 1, half = t & 1;
  const int xb = half * 32;

  if (c < 32) {
    const float* src = x1 + (((b * 32 + c) << 12) + i0 + xb);
    float* dst = &gft[c * 68 + xb];
    #pragma unroll
    for (int k = 0; k < 8; k++) ((float4*)dst)[k] = ((const float4*)src)[k];
  } else {
    const float* base; int S, cs;
    if (c < 64)      { base = x2; S = 32; cs = c - 32; }
    else if (c < 96) { base = x3; S = 16; cs = c - 64; }
    else             { base = x4; S = 8;  cs = c - 96; }
    const float* plane = base + (b * 32 + cs) * S * S;
    const int oy = i0 >> 6;                       // fixed for the whole block
    float yf = (float)oy * (float)(S - 1) * (1.0f / 63.0f);
    int y0 = (int)yf; if (y0 > S - 1) y0 = S - 1;
    int y1 = y0 + 1;  if (y1 > S - 1) y1 = S - 1;
    float wy = yf - (float)y0;
    const float* r0 = plane + y0 * S;
    const float* r1 = plane + y1 * S;
    float* dst = &gft[c * 68 + xb];
    for (int k = 0; k < 32; k++) {
      int ox = xb + k;
      float xf = (float)ox * (float)(S - 1) * (1.0f / 63.0f);
      int xx0 = (int)xf; if (xx0 > S - 1) xx0 = S - 1;
      int xx1 = xx0 + 1; if (xx1 > S - 1) xx1 = S - 1;
      float wx = xf - (float)xx0;
      float top = r0[xx0] + wx * (r0[xx1] - r0[xx0]);
      float bot = r1[xx0] + wx * (r1[xx1] - r1[xx0]);
      dst[k] = top + wy * (bot - top);
    }
  }
  __syncthreads();

  const int pos = t & 63, g = t >> 6;
  const int i = i0 + pos;
  for (int grp = 0; grp < 6; grp++) {
    const int oc0 = g * 48 + grp * 8;     // 8-aligned, never straddles q/k/v
    float acc[8];
    #pragma unroll
    for (int j = 0; j < 8; j++) acc[j] = bqkv[oc0 + j];
    #pragma unroll 8
    for (int c2 = 0; c2 < 128; c2++) {
      float v = gft[c2 * 68 + pos];
      float4 w0 = *(const float4*)&WT1[c2 * 192 + oc0];
      float4 w1 = *(const float4*)&WT1[c2 * 192 + oc0 + 4];
      acc[0] += w0.x * v; acc[1] += w0.y * v; acc[2] += w0.z * v; acc[3] += w0.w * v;
      acc[4] += w1.x * v; acc[5] += w1.y * v; acc[6] += w1.z * v; acc[7] += w1.w * v;
    }
    if (oc0 < 128) {  // Q or K, layout (b, i, c) bf16, 16B packed store
      unsigned int h0 = f2bf(acc[0]) | (f2bf(acc[1]) << 16);
      unsigned int h1 = f2bf(acc[2]) | (f2bf(acc[3]) << 16);
      unsigned int h2 = f2bf(acc[4]) | (f2bf(acc[5]) << 16);
      unsigned int h3 = f2bf(acc[6]) | (f2bf(acc[7]) << 16);
      uint4 pk = make_uint4(h0, h1, h2, h3);
      if (oc0 < 64) *(uint4*)&Qg[(((b << 12) + i) << 6) + oc0] = pk;
      else          *(uint4*)&Kg[(((b << 12) + i) << 6) + (oc0 - 64)] = pk;
    } else {          // V transposed (b, c, j): coalesced along pos
      int ocv = oc0 - 128;
      #pragma unroll
      for (int j = 0; j < 8; j++)
        Vg[(((b * 64 + ocv + j)) << 12) + i] = (unsigned short)f2bf(acc[j]);
    }
  }
}

// ---------------------------------------------------------------------------
// K2: flash attention, transposed formulation (S^T = K*Q^T, O^T = V^T*P^T).
// Per block: 4 waves x 32 queries = 128 queries; grid = 8*32 = 256.
// Per iter: 64 keys. LDS: K(key,dim)+Vt(dim,key) stride-72 bf16, P per wave.
// Softmax stats are per-lane (query == C-layout column): 2 shuffles only.
// ---------------------------------------------------------------------------
__global__ __launch_bounds__(256) void k_attn(
    const unsigned short* __restrict__ Qg, const unsigned short* __restrict__ Kg,
    const unsigned short* __restrict__ Vg, float* __restrict__ Og) {
  __shared__ __align__(16) unsigned short Kl[64 * 72];
  __shared__ __align__(16) unsigned short Vl[64 * 72];
  __shared__ __align__(16) unsigned short Pl[4][32 * 72];

  const int b = blockIdx.x >> 5;
  const int i0 = (blockIdx.x & 31) << 7;
  const int t = threadIdx.x;
  const int wv = t >> 6, lane = t & 63;
  const int r = lane & 15, qd = lane >> 4;
  const int qbase = i0 + wv * 32;

  // Q fragments (B-operand: n=query=lane&15, k=dim=qd*8+j), held in regs.
  s16x8 qf[2][2];
  #pragma unroll
  for (int nt = 0; nt < 2; nt++)
    #pragma unroll
    for (int ks = 0; ks < 2; ks++)
      qf[nt][ks] = *(const s16x8*)&Qg[(((b << 12) + qbase + nt * 16 + r) << 6) + ks * 32 + qd * 8];

  f32x4 zf = {0.f, 0.f, 0.f, 0.f};
  f32x4 acc[2][4];
  #pragma unroll
  for (int nt = 0; nt < 2; nt++)
    #pragma unroll
    for (int mt = 0; mt < 4; mt++) acc[nt][mt] = zf;
  float m[2] = {-1e30f, -1e30f};
  float l[2] = {0.f, 0.f};

  // staging: thread t -> key/dim row (t>>3) and (t>>3)+32, 16B seg t&7.
  const int srow = t >> 3, sseg = t & 7;
  const unsigned short* kt0 = &Kg[(((b << 12) + srow) << 6) + sseg * 8];
  const unsigned short* vt0 = &Vg[((b * 64 + srow) << 12) + sseg * 8];
  uint4 pk0 = *(const uint4*)(kt0);
  uint4 pk1 = *(const uint4*)(kt0 + (32 << 6));
  uint4 pv0 = *(const uint4*)(vt0);
  uint4 pv1 = *(const uint4*)(vt0 + (32 << 12));

  for (int it = 0; it < 64; it++) {
    __syncthreads();                         // waves done reading prev tile
    *(uint4*)&Kl[srow * 72 + sseg * 8] = pk0;
    *(uint4*)&Kl[(srow + 32) * 72 + sseg * 8] = pk1;
    *(uint4*)&Vl[srow * 72 + sseg * 8] = pv0;
    *(uint4*)&Vl[(srow + 32) * 72 + sseg * 8] = pv1;
    __syncthreads();                         // tile visible
    if (it < 63) {                           // prefetch next tile into VGPRs
      int j0 = (it + 1) << 6;
      pk0 = *(const uint4*)(kt0 + (j0 << 6));
      pk1 = *(const uint4*)(kt0 + ((j0 + 32) << 6));
      pv0 = *(const uint4*)(vt0 + j0);
      pv1 = *(const uint4*)(vt0 + (32 << 12) + j0);
    }

    // S^T tiles: D[m=key][n=query]; A-frag K: m=lane&15, k=qd*8+j
    f32x4 st[4][2];
    #pragma unroll
    for (int mt = 0; mt < 4; mt++) {
      s16x8 kf0 = *(const s16x8*)&Kl[(mt * 16 + r) * 72 + qd * 8];
      s16x8 kf1 = *(const s16x8*)&Kl[(mt * 16 + r) * 72 + 32 + qd * 8];
      #pragma unroll
      for (int nt = 0; nt < 2; nt++) {
        f32x4 s = __builtin_amdgcn_mfma_f32_16x16x32_bf16(kf0, qf[nt][0], zf, 0, 0, 0);
        s = __builtin_amdgcn_mfma_f32_16x16x32_bf16(kf1, qf[nt][1], s, 0, 0, 0);
        st[mt][nt] = s;
      }
    }

    // online softmax per query (= per lane col), logits pre-scaled by log2e
    #pragma unroll
    for (int nt = 0; nt < 2; nt++) {
      float cmax = st[0][nt].x;
      #pragma unroll
      for (int mt = 0; mt < 4; mt++) {
        cmax = fmaxf(cmax, st[mt][nt].x); cmax = fmaxf(cmax, st[mt][nt].y);
        cmax = fmaxf(cmax, st[mt][nt].z); cmax = fmaxf(cmax, st[mt][nt].w);
      }
      cmax = fmaxf(cmax, __shfl_xor(cmax, 16));
      cmax = fmaxf(cmax, __shfl_xor(cmax, 32));
      float mnew = fmaxf(m[nt], cmax);
      float alpha = exp2f(m[nt] - mnew);
      m[nt] = mnew;
      float rs = 0.f;
      #pragma unroll
      for (int mt = 0; mt < 4; mt++) {
        f32x4 p;
        p.x = exp2f(st[mt][nt].x - mnew);
        p.y = exp2f(st[mt][nt].y - mnew);
        p.z = exp2f(st[mt][nt].z - mnew);
        p.w = exp2f(st[mt][nt].w - mnew);
        rs += (p.x + p.y) + (p.z + p.w);
        uint2 w;                              // 4 consecutive keys -> b64 write
        w.x = f2bf(p.x) | (f2bf(p.y) << 16);
        w.y = f2bf(p.z) | (f2bf(p.w) << 16);
        *(uint2*)&Pl[wv][(nt * 16 + r) * 72 + mt * 16 + qd * 4] = w;
      }
      rs += __shfl_xor(rs, 16);
      rs += __shfl_xor(rs, 32);
      l[nt] = l[nt] * alpha + rs;
      #pragma unroll
      for (int mt = 0; mt < 4; mt++) {
        acc[nt][mt].x *= alpha; acc[nt][mt].y *= alpha;
        acc[nt][mt].z *= alpha; acc[nt][mt].w *= alpha;
      }
    }
    __builtin_amdgcn_wave_barrier();          // keep P writes before reads

    // O^T += V^T * P^T  (A-frag Vt: m=dim; B-frag P: n=query, 8 contig keys)
    #pragma unroll
    for (int ks = 0; ks < 2; ks++) {
      s16x8 pf0 = *(const s16x8*)&Pl[wv][(r) * 72 + ks * 32 + qd * 8];
      s16x8 pf1 = *(const s16x8*)&Pl[wv][(16 + r) * 72 + ks * 32 + qd * 8];
      #pragma unroll
      for (int mt = 0; mt < 4; mt++) {
        s16x8 vf = *(const s16x8*)&Vl[(mt * 16 + r) * 72 + ks * 32 + qd * 8];
        acc[0][mt] = __builtin_amdgcn_mfma_f32_16x16x32_bf16(vf, pf0, acc[0][mt], 0, 0, 0);
        acc[1][mt] = __builtin_amdgcn_mfma_f32_16x16x32_bf16(vf, pf1, acc[1][mt], 0, 0, 0);
      }
    }
  }

  // epilogue: O(b,i,c); lane holds query = qbase+nt*16+r, dims mt*16+qd*4+reg
  #pragma unroll
  for (int nt = 0; nt < 2; nt++) {
    float inv = 1.0f / l[nt];
    int qrow = (b << 12) + qbase + nt * 16 + r;
    #pragma unroll
    for (int mt = 0; mt < 4; mt++) {
      float4 o;
      o.x = acc[nt][mt].x * inv; o.y = acc[nt][mt].y * inv;
      o.z = acc[nt][mt].z * inv; o.w = acc[nt][mt].w * inv;
      *(float4*)&Og[(qrow << 6) + mt * 16 + qd * 4] = o;
    }
  }
}

// ---------------------------------------------------------------------------
// K3: fused out-proj -> relu(g1) -> sigmoid(g2). Block: (b, 64 positions),
// 4 threads/position split output channels. O row kept in registers.
// ---------------------------------------------------------------------------
__global__ __launch_bounds__(256) void k_out(
    const float* __restrict__ Og, const float* __restrict__ ow,
    const float* __restrict__ obias, const float* __restrict__ g1wT,
    const float* __restrict__ g1b, const float* __restrict__ g2wT,
    const float* __restrict__ g2b, float* __restrict__ SW) {
  __shared__ float gf2t[128 * 64];
  __shared__ float ht[32 * 64];
  const int b = blockIdx.x >> 6;
  const int i0 = (blockIdx.x & 63) << 6;
  const int t = threadIdx.x;
  const int pos = t & 63, g = t >> 6;
  const int i = i0 + pos;

  float4 o4[16];
  const float4* orow = (const float4*)&Og[(((b << 12) + i)) << 6];
  #pragma unroll
  for (int k = 0; k < 16; k++) o4[k] = orow[k];

  // phase A: gf2 = ow * O + ob   (each thread: 32 channels of 128)
  #pragma unroll 1
  for (int jc = 0; jc < 4; jc++) {
    float a8[8];
    #pragma unroll
    for (int j = 0; j < 8; j++) a8[j] = obias[g * 32 + jc * 8 + j];
    #pragma unroll
    for (int j = 0; j < 8; j++) {
      const float4* w = (const float4*)&ow[((g * 32 + jc * 8 + j)) << 6];
      float a = a8[j];
      #pragma unroll
      for (int k = 0; k < 16; k++) {
        float4 wk = w[k];
        a += wk.x * o4[k].x + wk.y * o4[k].y + wk.z * o4[k].z + wk.w * o4[k].w;
      }
      gf2t[(g * 32 + jc * 8 + j) * 64 + pos] = a;
    }
  }
  __syncthreads();

  // phase B: h = relu(g1w * gf2 + g1b)   (each thread: 8 of 32 channels)
  {
    float a8[8];
    #pragma unroll
    for (int j = 0; j < 8; j++) a8[j] = g1b[g * 8 + j];
    #pragma unroll 4
    for (int c = 0; c < 128; c++) {
      float v = gf2t[c * 64 + pos];
      float4 w0 = *(const float4*)&g1wT[(c << 5) + g * 8];
      float4 w1 = *(const float4*)&g1wT[(c << 5) + g * 8 + 4];
      a8[0] += w0.x * v; a8[1] += w0.y * v; a8[2] += w0.z * v; a8[3] += w0.w * v;
      a8[4] += w1.x * v; a8[5] += w1.y * v; a8[6] += w1.z * v; a8[7] += w1.w * v;
    }
    #pragma unroll
    for (int j = 0; j < 8; j++) ht[(g * 8 + j) * 64 + pos] = fmaxf(a8[j], 0.f);
  }
  __syncthreads();

  // phase C: sw = sigmoid(g2w * h + g2b)  (each thread: 32 of 128 channels)
  #pragma unroll 1
  for (int jc = 0; jc < 4; jc++) {
    float a8[8];
    #pragma unroll
    for (int j = 0; j < 8; j++) a8[j] = g2b[g * 32 + jc * 8 + j];
    #pragma unroll 4
    for (int c = 0; c < 32; c++) {
      float v = ht[c * 64 + pos];
      float4 w0 = *(const float4*)&g2wT[(c << 7) + g * 32 + jc * 8];
      float4 w1 = *(const float4*)&g2wT[(c << 7) + g * 32 + jc * 8 + 4];
      a8[0] += w0.x * v; a8[1] += w0.y * v; a8[2] += w0.z * v; a8[3] += w0.w * v;
      a8[4] += w1.x * v; a8[5] += w1.y * v; a8[6] += w1.z * v; a8[7] += w1.w * v;
    }
    #pragma unroll
    for (int j = 0; j < 8; j++) {
      float s = 1.0f / (1.0f + exp2f(-LOG2E * a8[j]));
      SW[(((b * 128 + g * 32 + jc * 8 + j)) << 12) + i] = s;
    }
  }
}

// ---------------------------------------------------------------------------
// K4: gated outputs: x1*(1+w1), x_k*(1+downsample(w_k)).
// ---------------------------------------------------------------------------
__device__ __forceinline__ float bilin64(const float* __restrict__ p, int oy, int ox, int n) {
  float yf = (float)oy * 63.0f / (float)n;
  int y0 = (int)yf; if (y0 > 63) y0 = 63;
  int y1 = y0 + 1;  if (y1 > 63) y1 = 63;
  float wy = yf - (float)y0;
  float xf = (float)ox * 63.0f / (float)n;
  int x0 = (int)xf; if (x0 > 63) x0 = 63;
  int x1 = x0 + 1;  if (x1 > 63) x1 = 63;
  float wx = xf - (float)x0;
  float v00 = p[y0 * 64 + x0], v01 = p[y0 * 64 + x1];
  float v10 = p[y1 * 64 + x0], v11 = p[y1 * 64 + x1];
  float top = v00 + wx * (v01 - v00);
  float bot = v10 + wx * (v11 - v10);
  return top + wy * (bot - top);
}

__global__ __launch_bounds__(256) void k_final(
    const float* __restrict__ x1, const float* __restrict__ x2,
    const float* __restrict__ x3, const float* __restrict__ x4,
    const float* __restrict__ SW, float* __restrict__ out) {
  const int N1 = 1048576, N2 = 262144, N3 = 65536, N4 = 16384;
  int idx = blockIdx.x * 256 + threadIdx.x;
  if (idx < N1) {
    int b = idx >> 17, rr = idx & 131071;
    int c = rr >> 12, hw = rr & 4095;
    out[idx] = x1[idx] * (1.f + SW[((b * 128 + c) << 12) + hw]);
  } else if (idx < N1 + N2) {
    int i2 = idx - N1;
    int b = i2 >> 15, rr = i2 & 32767;
    int c = rr >> 10, oy = (rr >> 5) & 31, ox = rr & 31;
    float w = bilin64(SW + ((b * 128 + 32 + c) << 12), oy, ox, 31);
    out[idx] = x2[i2] * (1.f + w);
  } else if (idx < N1 + N2 + N3) {
    int i3 = idx - N1 - N2;
    int b = i3 >> 13, rr = i3 & 8191;
    int c = rr >> 8, oy = (rr >> 4) & 15, ox = rr & 15;
    float w = bilin64(SW + ((b * 128 + 64 + c) << 12), oy, ox, 15);
    out[idx] = x3[i3] * (1.f + w);
  } else if (idx < N1 + N2 + N3 + N4) {
    int i4 = idx - N1 - N2 - N3;
    int b = i4 >> 11, rr = i4 & 2047;
    int c = rr >> 6, oy = (rr >> 3) & 7, ox = rr & 7;
    float w = bilin64(SW + ((b * 128 + 96 + c) << 12), oy, ox, 7);
    out[idx] = x4[i4] * (1.f + w);
  }
}

// ---------------------------------------------------------------------------
extern "C" void kernel_launch(void* const* d_in, const int* in_sizes, int n_in,
                              void* d_out, int out_size, void* d_ws, size_t ws_size,
                              hipStream_t stream) {
  const float* x1  = (const float*)d_in[0];
  const float* x2  = (const float*)d_in[1];
  const float* x3  = (const float*)d_in[2];
  const float* x4  = (const float*)d_in[3];
  const float* qw  = (const float*)d_in[4];
  const float* qb  = (const float*)d_in[5];
  const float* kw  = (const float*)d_in[6];
  const float* kb  = (const float*)d_in[7];
  const float* vw  = (const float*)d_in[8];
  const float* vb  = (const float*)d_in[9];
  const float* ow  = (const float*)d_in[10];
  const float* ob  = (const float*)d_in[11];
  const float* g1w = (const float*)d_in[12];
  const float* g1b = (const float*)d_in[13];
  const float* g2w = (const float*)d_in[14];
  const float* g2b = (const float*)d_in[15];
  float* out = (float*)d_out;

  char* ws = (char*)d_ws;
  unsigned short* Qg = (unsigned short*)(ws + 0);
  unsigned short* Kg = (unsigned short*)(ws + 4194304);
  unsigned short* Vg = (unsigned short*)(ws + 8388608);
  float* Og   = (float*)(ws + 12582912);
  float* SW   = (float*)(ws + 20971520);
  float* WT1  = (float*)(ws + 37748736);
  float* bqkv = (float*)(ws + 37847040);
  float* g1wT = (float*)(ws + 37848064);
  float* g2wT = (float*)(ws + 37864448);

  k_prep<<<96, 256, 0, stream>>>(qw, qb, kw, kb, vw, vb, g1w, g2w,
                                 WT1, bqkv, g1wT, g2wT);
  k_qkv<<<512, 256, 0, stream>>>(x1, x2, x3, x4, WT1, bqkv, Qg, Kg, Vg);
  k_attn<<<256, 256, 0, stream>>>(Qg, Kg, Vg, Og);
  k_out<<<512, 256, 0, stream>>>(Og, ow, ob, g1wT, g1b, g2wT, g2b, SW);
  k_final<<<5440, 256, 0, stream>>>(x1, x2, x3, x4, SW, out);
}

// Round 2
// 345.543 us; speedup vs baseline: 1.1677x; 1.1677x over previous
//
#include <hip/hip_runtime.h>
#include <hip/hip_bf16.h>

// ---------------------------------------------------------------------------
// DynamicFeaturePyramid forward, MI355X.
// attention: B=8, S=4096, D=64 single head; flash-fused bf16 MFMA,
// key-split x4 (no-max softmax -> partials combine by plain weighted sum).
// Workspace (bytes):
//   Q   (b,i,c) bf16  :        0 ..  4194304   } phase 1
//   K   (b,j,c) bf16  :  4194304 ..  8388608   }
//   Vt  (b,c,j) bf16  :  8388608 .. 12582912   }
//   SWb (b,c,i) bf16  :        0 ..  8388608   } phase 2 (aliases Q/K, dead)
//   Op  (p,b,i,c)bf16 : 12582912 .. 29360128   (per-part normalized O)
//   Lp  (p,b,i) fp32  : 29360128 .. 29884416
//   WT1 (c,192) fp32  : 29884416 .. 29982720
//   bqkv(192)   fp32  : 29982720 .. 29983744
//   g1wT(c,32)  fp32  : 29983744 .. 30000128
//   g2wT(c,128) fp32  : 30000128 .. 30016512
// ---------------------------------------------------------------------------

typedef __attribute__((ext_vector_type(8))) short s16x8;   // 8 bf16 = 4 VGPRs
typedef __attribute__((ext_vector_type(4))) float f32x4;   // MFMA C/D frag

#define LOG2E 1.44269504088896340736f

__device__ __forceinline__ unsigned int f2bf(float f) {
    unsigned int u = __float_as_uint(f);
    u += 0x7fffu + ((u >> 16) & 1u);   // RNE (inputs finite)
    return u >> 16;
}
__device__ __forceinline__ unsigned int pk2bf(float a, float b) {
    union { __hip_bfloat162 h; unsigned int u; } cv;
    cv.h = __float22bfloat162_rn(make_float2(a, b));   // v_cvt_pk_bf16_f32
    return cv.u;
}
__device__ __forceinline__ float bf2f(unsigned short u) {
    return __uint_as_float((unsigned int)u << 16);
}

// ---------------------------------------------------------------------------
// K0: weight prep (transpose + log2e fold).
// ---------------------------------------------------------------------------
__global__ __launch_bounds__(256) void k_prep(
    const float* __restrict__ qw, const float* __restrict__ qb,
    const float* __restrict__ kw, const float* __restrict__ kb,
    const float* __restrict__ vw, const float* __restrict__ vb,
    const float* __restrict__ g1w, const float* __restrict__ g2w,
    float* __restrict__ WT1, float* __restrict__ bqkv,
    float* __restrict__ g1wT, float* __restrict__ g2wT) {
  int t = blockIdx.x * 256 + threadIdx.x;
  if (t < 128 * 192) {            // WT1[c][oc], oc in [q64|k64|v64]
    int c = t / 192, oc = t % 192;
    float v;
    if (oc < 64)       v = qw[oc * 128 + c] * LOG2E;
    else if (oc < 128) v = kw[(oc - 64) * 128 + c];
    else               v = vw[(oc - 128) * 128 + c];
    WT1[t] = v;
  }
  if (t < 192) {
    float v;
    if (t < 64)       v = qb[t] * LOG2E;
    else if (t < 128) v = kb[t - 64];
    else              v = vb[t - 128];
    bqkv[t] = v;
  }
  if (t < 128 * 32) { int c = t >> 5, oc = t & 31;  g1wT[t] = g1w[oc * 128 + c]; }
  if (t < 32 * 128) { int c = t >> 7, oc = t & 127; g2wT[t] = g2w[oc * 32 + c]; }
}

// ---------------------------------------------------------------------------
// K1: fused (bilinear-upsample + concat) -> gf tile in LDS -> QKV projection.
// ---------------------------------------------------------------------------
__global__ __launch_bounds__(256) void k_qkv(
    const float* __restrict__ x1, const float* __restrict__ x2,
    const float* __restrict__ x3, const float* __restrict__ x4,
    const float* __restrict__ WT1, const float* __restrict__ bqkv,
    unsigned short* __restrict__ Qg, unsigned short* __restrict__ Kg,
    unsigned short* __restrict__ Vg) {
  __shared__ float gft[128 * 68];
  const int b = blockIdx.x >> 6;
  const int i0 = (blockIdx.x & 63) << 6;
  const int t = threadIdx.x;
  const int c = t >> 1, half = t & 1;
  const int xb = half * 32;

  if (c < 32) {
    const float* src = x1 + (((b * 32 + c) << 12) + i0 + xb);
    float* dst = &gft[c * 68 + xb];
    #pragma unroll
    for (int k = 0; k < 8; k++) ((float4*)dst)[k] = ((const float4*)src)[k];
  } else {
    const float* base; int S, cs;
    if (c < 64)      { base = x2; S = 32; cs = c - 32; }
    else if (c < 96) { base = x3; S = 16; cs = c - 64; }
    else             { base = x4; S = 8;  cs = c - 96; }
    const float* plane = base + (b * 32 + cs) * S * S;
    const int oy = i0 >> 6;
    float yf = (float)oy * (float)(S - 1) * (1.0f / 63.0f);
    int y0 = (int)yf; if (y0 > S - 1) y0 = S - 1;
    int y1 = y0 + 1;  if (y1 > S - 1) y1 = S - 1;
    float wy = yf - (float)y0;
    const float* r0 = plane + y0 * S;
    const float* r1 = plane + y1 * S;
    float* dst = &gft[c * 68 + xb];
    for (int k = 0; k < 32; k++) {
      int ox = xb + k;
      float xf = (float)ox * (float)(S - 1) * (1.0f / 63.0f);
      int xx0 = (int)xf; if (xx0 > S - 1) xx0 = S - 1;
      int xx1 = xx0 + 1; if (xx1 > S - 1) xx1 = S - 1;
      float wx = xf - (float)xx0;
      float top = r0[xx0] + wx * (r0[xx1] - r0[xx0]);
      float bot = r1[xx0] + wx * (r1[xx1] - r1[xx0]);
      dst[k] = top + wy * (bot - top);
    }
  }
  __syncthreads();

  const int pos = t & 63, g = t >> 6;
  const int i = i0 + pos;
  for (int grp = 0; grp < 6; grp++) {
    const int oc0 = g * 48 + grp * 8;
    float acc[8];
    #pragma unroll
    for (int j = 0; j < 8; j++) acc[j] = bqkv[oc0 + j];
    #pragma unroll 8
    for (int c2 = 0; c2 < 128; c2++) {
      float v = gft[c2 * 68 + pos];
      float4 w0 = *(const float4*)&WT1[c2 * 192 + oc0];
      float4 w1 = *(const float4*)&WT1[c2 * 192 + oc0 + 4];
      acc[0] += w0.x * v; acc[1] += w0.y * v; acc[2] += w0.z * v; acc[3] += w0.w * v;
      acc[4] += w1.x * v; acc[5] += w1.y * v; acc[6] += w1.z * v; acc[7] += w1.w * v;
    }
    if (oc0 < 128) {
      unsigned int h0 = pk2bf(acc[0], acc[1]);
      unsigned int h1 = pk2bf(acc[2], acc[3]);
      unsigned int h2 = pk2bf(acc[4], acc[5]);
      unsigned int h3 = pk2bf(acc[6], acc[7]);
      uint4 pk = make_uint4(h0, h1, h2, h3);
      if (oc0 < 64) *(uint4*)&Qg[(((b << 12) + i) << 6) + oc0] = pk;
      else          *(uint4*)&Kg[(((b << 12) + i) << 6) + (oc0 - 64)] = pk;
    } else {
      int ocv = oc0 - 128;
      #pragma unroll
      for (int j = 0; j < 8; j++)
        Vg[(((b * 64 + ocv + j)) << 12) + i] = (unsigned short)f2bf(acc[j]);
    }
  }
}

// ---------------------------------------------------------------------------
// K2: flash attention, transposed (S^T = K*Q^T, O^T = V^T*P^T), key-split x4.
// Grid 1024: blk -> b(>>7), part((>>5)&3), qg(&31). 4 blocks/CU, 4 waves/SIMD.
// No-max softmax: P = exp2(s) directly (exact up to power-of-2 scaling);
// per-part output stored normalized (bf16) + l (fp32); combine in k_out.
// ---------------------------------------------------------------------------
__global__ __launch_bounds__(256, 4) void k_attn(
    const unsigned short* __restrict__ Qg, const unsigned short* __restrict__ Kg,
    const unsigned short* __restrict__ Vg, unsigned short* __restrict__ Op,
    float* __restrict__ Lp) {
  __shared__ __align__(16) unsigned short Kl[64 * 72];
  __shared__ __align__(16) unsigned short Vl[64 * 72];
  __shared__ __align__(16) unsigned short Pl[4][32 * 72];

  const int b = blockIdx.x >> 7;
  const int part = (blockIdx.x >> 5) & 3;
  const int qg = blockIdx.x & 31;
  const int i0 = qg << 7;
  const int t = threadIdx.x;
  const int wv = t >> 6, lane = t & 63;
  const int r = lane & 15, qd = lane >> 4;
  const int qbase = i0 + wv * 32;

  // Q fragments (B-operand: n=query=lane&15, k=dim=qd*8+j)
  s16x8 qf[2][2];
  #pragma unroll
  for (int nt = 0; nt < 2; nt++)
    #pragma unroll
    for (int ks = 0; ks < 2; ks++)
      qf[nt][ks] = *(const s16x8*)&Qg[(((b << 12) + qbase + nt * 16 + r) << 6) + ks * 32 + qd * 8];

  f32x4 zf = {0.f, 0.f, 0.f, 0.f};
  f32x4 acc[2][4];
  #pragma unroll
  for (int nt = 0; nt < 2; nt++)
    #pragma unroll
    for (int mt = 0; mt < 4; mt++) acc[nt][mt] = zf;
  float l[2] = {0.f, 0.f};

  const int srow = t >> 3, sseg = t & 7;
  const unsigned short* kt0 = &Kg[(((b << 12) + (part << 10) + srow) << 6) + sseg * 8];
  const unsigned short* vt0 = &Vg[((b * 64 + srow) << 12) + (part << 10) + sseg * 8];
  uint4 pk0 = *(const uint4*)(kt0);
  uint4 pk1 = *(const uint4*)(kt0 + (32 << 6));
  uint4 pv0 = *(const uint4*)(vt0);
  uint4 pv1 = *(const uint4*)(vt0 + (32 << 12));

  for (int it = 0; it < 16; it++) {
    __syncthreads();
    *(uint4*)&Kl[srow * 72 + sseg * 8] = pk0;
    *(uint4*)&Kl[(srow + 32) * 72 + sseg * 8] = pk1;
    *(uint4*)&Vl[srow * 72 + sseg * 8] = pv0;
    *(uint4*)&Vl[(srow + 32) * 72 + sseg * 8] = pv1;
    __syncthreads();
    if (it < 15) {
      int j0 = (it + 1) << 6;
      pk0 = *(const uint4*)(kt0 + (j0 << 6));
      pk1 = *(const uint4*)(kt0 + ((j0 + 32) << 6));
      pv0 = *(const uint4*)(vt0 + j0);
      pv1 = *(const uint4*)(vt0 + (32 << 12) + j0);
    }

    // S^T tiles: D[m=key][n=query]
    f32x4 st[4][2];
    #pragma unroll
    for (int mt = 0; mt < 4; mt++) {
      s16x8 kf0 = *(const s16x8*)&Kl[(mt * 16 + r) * 72 + qd * 8];
      s16x8 kf1 = *(const s16x8*)&Kl[(mt * 16 + r) * 72 + 32 + qd * 8];
      #pragma unroll
      for (int nt = 0; nt < 2; nt++) {
        f32x4 s = __builtin_amdgcn_mfma_f32_16x16x32_bf16(kf0, qf[nt][0], zf, 0, 0, 0);
        s = __builtin_amdgcn_mfma_f32_16x16x32_bf16(kf1, qf[nt][1], s, 0, 0, 0);
        st[mt][nt] = s;
      }
    }

    // no-max softmax: p = 2^s (logits pre-scaled by log2e; |s| small here)
    #pragma unroll
    for (int nt = 0; nt < 2; nt++) {
      float rs = 0.f;
      #pragma unroll
      for (int mt = 0; mt < 4; mt++) {
        float px = exp2f(fminf(st[mt][nt].x, 80.f));
        float py = exp2f(fminf(st[mt][nt].y, 80.f));
        float pz = exp2f(fminf(st[mt][nt].z, 80.f));
        float pw = exp2f(fminf(st[mt][nt].w, 80.f));
        rs += (px + py) + (pz + pw);
        uint2 w;
        w.x = pk2bf(px, py);
        w.y = pk2bf(pz, pw);
        *(uint2*)&Pl[wv][(nt * 16 + r) * 72 + mt * 16 + qd * 4] = w;
      }
      rs += __shfl_xor(rs, 16);
      rs += __shfl_xor(rs, 32);
      l[nt] += rs;
    }
    __builtin_amdgcn_wave_barrier();

    // O^T += V^T * P^T
    #pragma unroll
    for (int ks = 0; ks < 2; ks++) {
      s16x8 pf0 = *(const s16x8*)&Pl[wv][(r) * 72 + ks * 32 + qd * 8];
      s16x8 pf1 = *(const s16x8*)&Pl[wv][(16 + r) * 72 + ks * 32 + qd * 8];
      #pragma unroll
      for (int mt = 0; mt < 4; mt++) {
        s16x8 vf = *(const s16x8*)&Vl[(mt * 16 + r) * 72 + ks * 32 + qd * 8];
        acc[0][mt] = __builtin_amdgcn_mfma_f32_16x16x32_bf16(vf, pf0, acc[0][mt], 0, 0, 0);
        acc[1][mt] = __builtin_amdgcn_mfma_f32_16x16x32_bf16(vf, pf1, acc[1][mt], 0, 0, 0);
      }
    }
  }

  // epilogue: per-part normalized O in bf16 + l in fp32
  #pragma unroll
  for (int nt = 0; nt < 2; nt++) {
    float inv = 1.0f / l[nt];
    int qrow = qbase + nt * 16 + r;
    unsigned short* orow = &Op[(((part * 8 + b) << 12) + qrow) << 6];
    #pragma unroll
    for (int mt = 0; mt < 4; mt++) {
      uint2 w;
      w.x = pk2bf(acc[nt][mt].x * inv, acc[nt][mt].y * inv);
      w.y = pk2bf(acc[nt][mt].z * inv, acc[nt][mt].w * inv);
      *(uint2*)&orow[mt * 16 + qd * 4] = w;
    }
    if (qd == 0) Lp[((part * 8 + b) << 12) + qrow] = l[nt];
  }
}

// ---------------------------------------------------------------------------
// K3: combine key-split partials -> out-proj -> relu(g1) -> sigmoid(g2) -> SW(bf16)
// ---------------------------------------------------------------------------
__global__ __launch_bounds__(256) void k_out(
    const unsigned short* __restrict__ Op, const float* __restrict__ Lp,
    const float* __restrict__ ow, const float* __restrict__ obias,
    const float* __restrict__ g1wT, const float* __restrict__ g1b,
    const float* __restrict__ g2wT, const float* __restrict__ g2b,
    unsigned short* __restrict__ SWb) {
  __shared__ float gf2t[128 * 64];
  __shared__ float ht[32 * 64];
  const int b = blockIdx.x >> 6;
  const int i0 = (blockIdx.x & 63) << 6;
  const int t = threadIdx.x;
  const int pos = t & 63, g = t >> 6;
  const int i = i0 + pos;

  // combine: O = sum_p (l_p / sum l) * o_p
  float lp4[4], lsum = 0.f;
  #pragma unroll
  for (int p = 0; p < 4; p++) { lp4[p] = Lp[((p * 8 + b) << 12) + i]; lsum += lp4[p]; }
  float o[64];
  #pragma unroll
  for (int k = 0; k < 64; k++) o[k] = 0.f;
  #pragma unroll
  for (int p = 0; p < 4; p++) {
    float w = lp4[p] / lsum;
    const uint2* prow = (const uint2*)&Op[(((p * 8 + b) << 12) + i) << 6];
    #pragma unroll
    for (int k = 0; k < 16; k++) {
      uint2 u = prow[k];
      o[k * 4 + 0] += w * __uint_as_float(u.x << 16);
      o[k * 4 + 1] += w * __uint_as_float(u.x & 0xFFFF0000u);
      o[k * 4 + 2] += w * __uint_as_float(u.y << 16);
      o[k * 4 + 3] += w * __uint_as_float(u.y & 0xFFFF0000u);
    }
  }

  // phase A: gf2 = ow * O + ob
  #pragma unroll 1
  for (int jc = 0; jc < 4; jc++) {
    #pragma unroll
    for (int j = 0; j < 8; j++) {
      const int oc = g * 32 + jc * 8 + j;
      const float4* w = (const float4*)&ow[oc << 6];
      float a = obias[oc];
      #pragma unroll
      for (int k = 0; k < 16; k++) {
        float4 wk = w[k];
        a += wk.x * o[k * 4] + wk.y * o[k * 4 + 1] + wk.z * o[k * 4 + 2] + wk.w * o[k * 4 + 3];
      }
      gf2t[oc * 64 + pos] = a;
    }
  }
  __syncthreads();

  // phase B: h = relu(g1w * gf2 + g1b)
  {
    float a8[8];
    #pragma unroll
    for (int j = 0; j < 8; j++) a8[j] = g1b[g * 8 + j];
    #pragma unroll 4
    for (int c = 0; c < 128; c++) {
      float v = gf2t[c * 64 + pos];
      float4 w0 = *(const float4*)&g1wT[(c << 5) + g * 8];
      float4 w1 = *(const float4*)&g1wT[(c << 5) + g * 8 + 4];
      a8[0] += w0.x * v; a8[1] += w0.y * v; a8[2] += w0.z * v; a8[3] += w0.w * v;
      a8[4] += w1.x * v; a8[5] += w1.y * v; a8[6] += w1.z * v; a8[7] += w1.w * v;
    }
    #pragma unroll
    for (int j = 0; j < 8; j++) ht[(g * 8 + j) * 64 + pos] = fmaxf(a8[j], 0.f);
  }
  __syncthreads();

  // phase C: sw = sigmoid(g2w * h + g2b) -> bf16
  #pragma unroll 1
  for (int jc = 0; jc < 4; jc++) {
    float a8[8];
    #pragma unroll
    for (int j = 0; j < 8; j++) a8[j] = g2b[g * 32 + jc * 8 + j];
    #pragma unroll 4
    for (int c = 0; c < 32; c++) {
      float v = ht[c * 64 + pos];
      float4 w0 = *(const float4*)&g2wT[(c << 7) + g * 32 + jc * 8];
      float4 w1 = *(const float4*)&g2wT[(c << 7) + g * 32 + jc * 8 + 4];
      a8[0] += w0.x * v; a8[1] += w0.y * v; a8[2] += w0.z * v; a8[3] += w0.w * v;
      a8[4] += w1.x * v; a8[5] += w1.y * v; a8[6] += w1.z * v; a8[7] += w1.w * v;
    }
    #pragma unroll
    for (int j = 0; j < 8; j++) {
      float s = 1.0f / (1.0f + exp2f(-LOG2E * a8[j]));
      SWb[(((b * 128 + g * 32 + jc * 8 + j)) << 12) + i] = (unsigned short)f2bf(s);
    }
  }
}

// ---------------------------------------------------------------------------
// K4: gated outputs: x1*(1+w1), x_k*(1+downsample(w_k)). SW is bf16.
// ---------------------------------------------------------------------------
__device__ __forceinline__ float bilin64(const unsigned short* __restrict__ p,
                                         int oy, int ox, int n) {
  float yf = (float)oy * 63.0f / (float)n;
  int y0 = (int)yf; if (y0 > 63) y0 = 63;
  int y1 = y0 + 1;  if (y1 > 63) y1 = 63;
  float wy = yf - (float)y0;
  float xf = (float)ox * 63.0f / (float)n;
  int x0 = (int)xf; if (x0 > 63) x0 = 63;
  int x1 = x0 + 1;  if (x1 > 63) x1 = 63;
  float wx = xf - (float)x0;
  float v00 = bf2f(p[y0 * 64 + x0]), v01 = bf2f(p[y0 * 64 + x1]);
  float v10 = bf2f(p[y1 * 64 + x0]), v11 = bf2f(p[y1 * 64 + x1]);
  float top = v00 + wx * (v01 - v00);
  float bot = v10 + wx * (v11 - v10);
  return top + wy * (bot - top);
}

__global__ __launch_bounds__(256) void k_final(
    const float* __restrict__ x1, const float* __restrict__ x2,
    const float* __restrict__ x3, const float* __restrict__ x4,
    const unsigned short* __restrict__ SWb, float* __restrict__ out) {
  const int N1 = 1048576, N2 = 262144, N3 = 65536, N4 = 16384;
  int idx = blockIdx.x * 256 + threadIdx.x;
  if (idx < N1) {
    int b = idx >> 17, rr = idx & 131071;
    int c = rr >> 12, hw = rr & 4095;
    out[idx] = x1[idx] * (1.f + bf2f(SWb[((b * 128 + c) << 12) + hw]));
  } else if (idx < N1 + N2) {
    int i2 = idx - N1;
    int b = i2 >> 15, rr = i2 & 32767;
    int c = rr >> 10, oy = (rr >> 5) & 31, ox = rr & 31;
    float w = bilin64(SWb + ((b * 128 + 32 + c) << 12), oy, ox, 31);
    out[idx] = x2[i2] * (1.f + w);
  } else if (idx < N1 + N2 + N3) {
    int i3 = idx - N1 - N2;
    int b = i3 >> 13, rr = i3 & 8191;
    int c = rr >> 8, oy = (rr >> 4) & 15, ox = rr & 15;
    float w = bilin64(SWb + ((b * 128 + 64 + c) << 12), oy, ox, 15);
    out[idx] = x3[i3] * (1.f + w);
  } else if (idx < N1 + N2 + N3 + N4) {
    int i4 = idx - N1 - N2 - N3;
    int b = i4 >> 11, rr = i4 & 2047;
    int c = rr >> 6, oy = (rr >> 3) & 7, ox = rr & 7;
    float w = bilin64(SWb + ((b * 128 + 96 + c) << 12), oy, ox, 7);
    out[idx] = x4[i4] * (1.f + w);
  }
}

// ---------------------------------------------------------------------------
extern "C" void kernel_launch(void* const* d_in, const int* in_sizes, int n_in,
                              void* d_out, int out_size, void* d_ws, size_t ws_size,
                              hipStream_t stream) {
  const float* x1  = (const float*)d_in[0];
  const float* x2  = (const float*)d_in[1];
  const float* x3  = (const float*)d_in[2];
  const float* x4  = (const float*)d_in[3];
  const float* qw  = (const float*)d_in[4];
  const float* qb  = (const float*)d_in[5];
  const float* kw  = (const float*)d_in[6];
  const float* kb  = (const float*)d_in[7];
  const float* vw  = (const float*)d_in[8];
  const float* vb  = (const float*)d_in[9];
  const float* ow  = (const float*)d_in[10];
  const float* ob  = (const float*)d_in[11];
  const float* g1w = (const float*)d_in[12];
  const float* g1b = (const float*)d_in[13];
  const float* g2w = (const float*)d_in[14];
  const float* g2b = (const float*)d_in[15];
  float* out = (float*)d_out;

  char* ws = (char*)d_ws;
  unsigned short* Qg  = (unsigned short*)(ws + 0);
  unsigned short* Kg  = (unsigned short*)(ws + 4194304);
  unsigned short* Vg  = (unsigned short*)(ws + 8388608);
  unsigned short* SWb = (unsigned short*)(ws + 0);          // aliases Q/K (dead)
  unsigned short* Op  = (unsigned short*)(ws + 12582912);
  float* Lp   = (float*)(ws + 29360128);
  float* WT1  = (float*)(ws + 29884416);
  float* bqkv = (float*)(ws + 29982720);
  float* g1wT = (float*)(ws + 29983744);
  float* g2wT = (float*)(ws + 30000128);

  k_prep<<<96, 256, 0, stream>>>(qw, qb, kw, kb, vw, vb, g1w, g2w,
                                 WT1, bqkv, g1wT, g2wT);
  k_qkv<<<512, 256, 0, stream>>>(x1, x2, x3, x4, WT1, bqkv, Qg, Kg, Vg);
  k_attn<<<1024, 256, 0, stream>>>(Qg, Kg, Vg, Op, Lp);
  k_out<<<512, 256, 0, stream>>>(Op, Lp, ow, ob, g1wT, g1b, g2wT, g2b, SWb);
  k_final<<<5440, 256, 0, stream>>>(x1, x2, x3, x4, SWb, out);
}

// Round 3
// 267.090 us; speedup vs baseline: 1.5107x; 1.2937x over previous
//
#include <hip/hip_runtime.h>
#include <hip/hip_bf16.h>

// ---------------------------------------------------------------------------
// DynamicFeaturePyramid forward, MI355X.
// attention: B=8, S=4096, D=64 single head; flash-fused bf16 MFMA,
// key-split x4 (no-max softmax -> partials combine by plain weighted sum).
// QKV projection is now an MFMA GEMM (W bf16 A-frags from global, gf tile
// staged bf16 [pos][c] in LDS).
// Workspace (bytes):
//   Q   (b,i,c) bf16  :        0 ..  4194304   } phase 1
//   K   (b,j,c) bf16  :  4194304 ..  8388608   }
//   Vt  (b,c,j) bf16  :  8388608 .. 12582912   }
//   SWb (b,c,i) bf16  :        0 ..  8388608   } phase 2 (aliases Q/K, dead)
//   Op  (p,b,i,c)bf16 : 12582912 .. 29360128   (per-part normalized O)
//   Lp  (p,b,i) fp32  : 29360128 .. 29884416
//   WTb (oc,c)  bf16  : 29884416 .. 29933568   (192x128, q rows *log2e)
//   bqkv(192)   fp32  : 29933568 .. 29934336 (pad to 29934592)
//   g1wT(c,32)  fp32  : 29934592 .. 29950976
//   g2wT(c,128) fp32  : 29950976 .. 29967360
// ---------------------------------------------------------------------------

typedef __attribute__((ext_vector_type(8))) short s16x8;   // 8 bf16 = 4 VGPRs
typedef __attribute__((ext_vector_type(4))) float f32x4;   // MFMA C/D frag

#define LOG2E 1.44269504088896340736f

__device__ __forceinline__ unsigned int f2bf(float f) {
    unsigned int u = __float_as_uint(f);
    u += 0x7fffu + ((u >> 16) & 1u);   // RNE (inputs finite)
    return u >> 16;
}
__device__ __forceinline__ unsigned int pk2bf(float a, float b) {
    union { __hip_bfloat162 h; unsigned int u; } cv;
    cv.h = __float22bfloat162_rn(make_float2(a, b));   // v_cvt_pk_bf16_f32
    return cv.u;
}
__device__ __forceinline__ float bf2f(unsigned short u) {
    return __uint_as_float((unsigned int)u << 16);
}

// ---------------------------------------------------------------------------
// K0: weight prep. WTb[oc][c] bf16 (q rows scaled by log2e), bias fp32,
// g1wT/g2wT fp32 transposed.
// ---------------------------------------------------------------------------
__global__ __launch_bounds__(256) void k_prep(
    const float* __restrict__ qw, const float* __restrict__ qb,
    const float* __restrict__ kw, const float* __restrict__ kb,
    const float* __restrict__ vw, const float* __restrict__ vb,
    const float* __restrict__ g1w, const float* __restrict__ g2w,
    unsigned short* __restrict__ WTb, float* __restrict__ bqkv,
    float* __restrict__ g1wT, float* __restrict__ g2wT) {
  int t = blockIdx.x * 256 + threadIdx.x;
  if (t < 192 * 128) {            // WTb[oc][c]
    int oc = t >> 7, c = t & 127;
    float v;
    if (oc < 64)       v = qw[oc * 128 + c] * LOG2E;
    else if (oc < 128) v = kw[(oc - 64) * 128 + c];
    else               v = vw[(oc - 128) * 128 + c];
    WTb[t] = (unsigned short)f2bf(v);
  }
  if (t < 192) {
    float v;
    if (t < 64)       v = qb[t] * LOG2E;
    else if (t < 128) v = kb[t - 64];
    else              v = vb[t - 128];
    bqkv[t] = v;
  }
  if (t < 128 * 32) { int c = t >> 5, oc = t & 31;  g1wT[t] = g1w[oc * 128 + c]; }
  if (t < 32 * 128) { int c = t >> 7, oc = t & 127; g2wT[t] = g2w[oc * 32 + c]; }
}

// ---------------------------------------------------------------------------
// K1: fused (bilinear-upsample + concat) -> gf bf16 tile [pos][c] in LDS ->
// MFMA QKV projection. Block: (b, 128 pos); grid 8*32=256.
// Staging: thread owns channel pair (2cp, 2cp+1) x 32 positions -> packed b32
// LDS writes. GEMM: wave w -> oc in [48w, 48w+48), 3 m-tiles x 8 n-tiles,
// A-frags (W) in regs from global, B-frags (gf) ds_read_b128.
// ---------------------------------------------------------------------------
__global__ __launch_bounds__(256) void k_qkv(
    const float* __restrict__ x1, const float* __restrict__ x2,
    const float* __restrict__ x3, const float* __restrict__ x4,
    const unsigned short* __restrict__ WTb, const float* __restrict__ bqkv,
    unsigned short* __restrict__ Qg, unsigned short* __restrict__ Kg,
    unsigned short* __restrict__ Vg) {
  __shared__ __align__(16) unsigned short gfb[128 * 136];   // [pos][c] stride 136
  unsigned int* gfbu = (unsigned int*)gfb;                  // word idx = pos*68 + cp

  const int b = blockIdx.x >> 5;
  const int i0 = (blockIdx.x & 31) << 7;
  const int t = threadIdx.x;

  // ---- staging: channel pair cp=(t>>2), quarter q=(t&3) -> 32 positions ----
  {
    const int cp = t >> 2, q = t & 3;
    const int c0 = cp << 1;
    const int pbase = q << 5;                 // local pos base
    const int oy = (i0 >> 6) + (q >> 1);      // global output row
    const int ox0 = (q & 1) << 5;             // x offset within row

    if (cp < 16) {                            // x1: direct copy, 2 channels
      const float* s0 = x1 + (((b * 32 + c0) << 12) + (oy << 6) + ox0);
      const float* s1 = s0 + 4096;
      #pragma unroll
      for (int k8 = 0; k8 < 8; k8++) {
        float4 va = ((const float4*)s0)[k8];
        float4 vb = ((const float4*)s1)[k8];
        int p = pbase + k8 * 4;
        gfbu[(p + 0) * 68 + cp] = pk2bf(va.x, vb.x);
        gfbu[(p + 1) * 68 + cp] = pk2bf(va.y, vb.y);
        gfbu[(p + 2) * 68 + cp] = pk2bf(va.z, vb.z);
        gfbu[(p + 3) * 68 + cp] = pk2bf(va.w, vb.w);
      }
    } else {                                  // bilinear upsample, 2 channels
      const float* base; int S, cs;
      if (cp < 32)      { base = x2; S = 32; cs = c0 - 32; }
      else if (cp < 48) { base = x3; S = 16; cs = c0 - 64; }
      else              { base = x4; S = 8;  cs = c0 - 96; }
      const float* pl0 = base + (b * 32 + cs) * S * S;
      const float* pl1 = pl0 + S * S;
      float yf = (float)oy * (float)(S - 1) * (1.0f / 63.0f);
      int y0 = (int)yf; if (y0 > S - 1) y0 = S - 1;
      int y1 = y0 + 1;  if (y1 > S - 1) y1 = S - 1;
      float wy = yf - (float)y0;
      const float* r00 = pl0 + y0 * S; const float* r01 = pl0 + y1 * S;
      const float* r10 = pl1 + y0 * S; const float* r11 = pl1 + y1 * S;
      for (int k = 0; k < 32; k++) {
        int ox = ox0 + k;
        float xf = (float)ox * (float)(S - 1) * (1.0f / 63.0f);
        int xx0 = (int)xf; if (xx0 > S - 1) xx0 = S - 1;
        int xx1 = xx0 + 1; if (xx1 > S - 1) xx1 = S - 1;
        float wx = xf - (float)xx0;
        float a0 = r00[xx0] + wx * (r00[xx1] - r00[xx0]);
        float b0 = r01[xx0] + wx * (r01[xx1] - r01[xx0]);
        float v0 = a0 + wy * (b0 - a0);
        float a1 = r10[xx0] + wx * (r10[xx1] - r10[xx0]);
        float b1 = r11[xx0] + wx * (r11[xx1] - r11[xx0]);
        float v1 = a1 + wy * (b1 - a1);
        gfbu[(pbase + k) * 68 + cp] = pk2bf(v0, v1);
      }
    }
  }
  __syncthreads();

  // ---- MFMA GEMM: D[m=oc][n=pos] = W x gf ----
  const int wv = t >> 6, lane = t & 63;
  const int r = lane & 15, qd = lane >> 4;
  const int ocb = wv * 48;

  s16x8 af[3][4];
  #pragma unroll
  for (int mti = 0; mti < 3; mti++)
    #pragma unroll
    for (int ks = 0; ks < 4; ks++)
      af[mti][ks] = *(const s16x8*)&WTb[(ocb + mti * 16 + r) * 128 + ks * 32 + qd * 8];
  float4 bias[3];
  #pragma unroll
  for (int mti = 0; mti < 3; mti++)
    bias[mti] = *(const float4*)&bqkv[ocb + mti * 16 + qd * 4];

  f32x4 zf = {0.f, 0.f, 0.f, 0.f};
  #pragma unroll 1
  for (int nt = 0; nt < 8; nt++) {
    s16x8 bfr[4];
    #pragma unroll
    for (int ks = 0; ks < 4; ks++)
      bfr[ks] = *(const s16x8*)&gfb[(nt * 16 + r) * 136 + ks * 32 + qd * 8];
    f32x4 acc[3] = {zf, zf, zf};
    #pragma unroll
    for (int ks = 0; ks < 4; ks++)
      #pragma unroll
      for (int mti = 0; mti < 3; mti++)
        acc[mti] = __builtin_amdgcn_mfma_f32_16x16x32_bf16(af[mti][ks], bfr[ks], acc[mti], 0, 0, 0);

    const int pos = i0 + nt * 16 + r;
    #pragma unroll
    for (int mti = 0; mti < 3; mti++) {
      const int gmt = wv * 3 + mti;           // global m-tile 0..11 (wave-uniform)
      float ax = acc[mti].x + bias[mti].x;
      float ay = acc[mti].y + bias[mti].y;
      float az = acc[mti].z + bias[mti].z;
      float aw = acc[mti].w + bias[mti].w;
      if (gmt < 4) {                          // Q: (b,pos,oc)
        uint2 w; w.x = pk2bf(ax, ay); w.y = pk2bf(az, aw);
        *(uint2*)&Qg[(((b << 12) + pos) << 6) + gmt * 16 + qd * 4] = w;
      } else if (gmt < 8) {                   // K: (b,pos,oc)
        uint2 w; w.x = pk2bf(ax, ay); w.y = pk2bf(az, aw);
        *(uint2*)&Kg[(((b << 12) + pos) << 6) + (gmt - 4) * 16 + qd * 4] = w;
      } else {                                // V^T: (b,oc,pos)
        int ocv = (gmt - 8) * 16 + qd * 4;
        Vg[((b * 64 + ocv + 0) << 12) + pos] = (unsigned short)f2bf(ax);
        Vg[((b * 64 + ocv + 1) << 12) + pos] = (unsigned short)f2bf(ay);
        Vg[((b * 64 + ocv + 2) << 12) + pos] = (unsigned short)f2bf(az);
        Vg[((b * 64 + ocv + 3) << 12) + pos] = (unsigned short)f2bf(aw);
      }
    }
  }
}

// ---------------------------------------------------------------------------
// K2: flash attention, transposed (S^T = K*Q^T, O^T = V^T*P^T), key-split x4.
// ---------------------------------------------------------------------------
__global__ __launch_bounds__(256, 4) void k_attn(
    const unsigned short* __restrict__ Qg, const unsigned short* __restrict__ Kg,
    const unsigned short* __restrict__ Vg, unsigned short* __restrict__ Op,
    float* __restrict__ Lp) {
  __shared__ __align__(16) unsigned short Kl[64 * 72];
  __shared__ __align__(16) unsigned short Vl[64 * 72];
  __shared__ __align__(16) unsigned short Pl[4][32 * 72];

  const int b = blockIdx.x >> 7;
  const int part = (blockIdx.x >> 5) & 3;
  const int qg = blockIdx.x & 31;
  const int i0 = qg << 7;
  const int t = threadIdx.x;
  const int wv = t >> 6, lane = t & 63;
  const int r = lane & 15, qd = lane >> 4;
  const int qbase = i0 + wv * 32;

  s16x8 qf[2][2];
  #pragma unroll
  for (int nt = 0; nt < 2; nt++)
    #pragma unroll
    for (int ks = 0; ks < 2; ks++)
      qf[nt][ks] = *(const s16x8*)&Qg[(((b << 12) + qbase + nt * 16 + r) << 6) + ks * 32 + qd * 8];

  f32x4 zf = {0.f, 0.f, 0.f, 0.f};
  f32x4 acc[2][4];
  #pragma unroll
  for (int nt = 0; nt < 2; nt++)
    #pragma unroll
    for (int mt = 0; mt < 4; mt++) acc[nt][mt] = zf;
  float l[2] = {0.f, 0.f};

  const int srow = t >> 3, sseg = t & 7;
  const unsigned short* kt0 = &Kg[(((b << 12) + (part << 10) + srow) << 6) + sseg * 8];
  const unsigned short* vt0 = &Vg[((b * 64 + srow) << 12) + (part << 10) + sseg * 8];
  uint4 pk0 = *(const uint4*)(kt0);
  uint4 pk1 = *(const uint4*)(kt0 + (32 << 6));
  uint4 pv0 = *(const uint4*)(vt0);
  uint4 pv1 = *(const uint4*)(vt0 + (32 << 12));

  for (int it = 0; it < 16; it++) {
    __syncthreads();
    *(uint4*)&Kl[srow * 72 + sseg * 8] = pk0;
    *(uint4*)&Kl[(srow + 32) * 72 + sseg * 8] = pk1;
    *(uint4*)&Vl[srow * 72 + sseg * 8] = pv0;
    *(uint4*)&Vl[(srow + 32) * 72 + sseg * 8] = pv1;
    __syncthreads();
    if (it < 15) {
      int j0 = (it + 1) << 6;
      pk0 = *(const uint4*)(kt0 + (j0 << 6));
      pk1 = *(const uint4*)(kt0 + ((j0 + 32) << 6));
      pv0 = *(const uint4*)(vt0 + j0);
      pv1 = *(const uint4*)(vt0 + (32 << 12) + j0);
    }

    f32x4 st[4][2];
    #pragma unroll
    for (int mt = 0; mt < 4; mt++) {
      s16x8 kf0 = *(const s16x8*)&Kl[(mt * 16 + r) * 72 + qd * 8];
      s16x8 kf1 = *(const s16x8*)&Kl[(mt * 16 + r) * 72 + 32 + qd * 8];
      #pragma unroll
      for (int nt = 0; nt < 2; nt++) {
        f32x4 s = __builtin_amdgcn_mfma_f32_16x16x32_bf16(kf0, qf[nt][0], zf, 0, 0, 0);
        s = __builtin_amdgcn_mfma_f32_16x16x32_bf16(kf1, qf[nt][1], s, 0, 0, 0);
        st[mt][nt] = s;
      }
    }

    #pragma unroll
    for (int nt = 0; nt < 2; nt++) {
      float rs = 0.f;
      #pragma unroll
      for (int mt = 0; mt < 4; mt++) {
        float px = exp2f(fminf(st[mt][nt].x, 80.f));
        float py = exp2f(fminf(st[mt][nt].y, 80.f));
        float pz = exp2f(fminf(st[mt][nt].z, 80.f));
        float pw = exp2f(fminf(st[mt][nt].w, 80.f));
        rs += (px + py) + (pz + pw);
        uint2 w;
        w.x = pk2bf(px, py);
        w.y = pk2bf(pz, pw);
        *(uint2*)&Pl[wv][(nt * 16 + r) * 72 + mt * 16 + qd * 4] = w;
      }
      rs += __shfl_xor(rs, 16);
      rs += __shfl_xor(rs, 32);
      l[nt] += rs;
    }
    __builtin_amdgcn_wave_barrier();

    #pragma unroll
    for (int ks = 0; ks < 2; ks++) {
      s16x8 pf0 = *(const s16x8*)&Pl[wv][(r) * 72 + ks * 32 + qd * 8];
      s16x8 pf1 = *(const s16x8*)&Pl[wv][(16 + r) * 72 + ks * 32 + qd * 8];
      #pragma unroll
      for (int mt = 0; mt < 4; mt++) {
        s16x8 vf = *(const s16x8*)&Vl[(mt * 16 + r) * 72 + ks * 32 + qd * 8];
        acc[0][mt] = __builtin_amdgcn_mfma_f32_16x16x32_bf16(vf, pf0, acc[0][mt], 0, 0, 0);
        acc[1][mt] = __builtin_amdgcn_mfma_f32_16x16x32_bf16(vf, pf1, acc[1][mt], 0, 0, 0);
      }
    }
  }

  #pragma unroll
  for (int nt = 0; nt < 2; nt++) {
    float inv = 1.0f / l[nt];
    int qrow = qbase + nt * 16 + r;
    unsigned short* orow = &Op[(((part * 8 + b) << 12) + qrow) << 6];
    #pragma unroll
    for (int mt = 0; mt < 4; mt++) {
      uint2 w;
      w.x = pk2bf(acc[nt][mt].x * inv, acc[nt][mt].y * inv);
      w.y = pk2bf(acc[nt][mt].z * inv, acc[nt][mt].w * inv);
      *(uint2*)&orow[mt * 16 + qd * 4] = w;
    }
    if (qd == 0) Lp[((part * 8 + b) << 12) + qrow] = l[nt];
  }
}

// ---------------------------------------------------------------------------
// K3: combine key-split partials -> out-proj -> relu(g1) -> sigmoid(g2) -> SW(bf16)
// ---------------------------------------------------------------------------
__global__ __launch_bounds__(256) void k_out(
    const unsigned short* __restrict__ Op, const float* __restrict__ Lp,
    const float* __restrict__ ow, const float* __restrict__ obias,
    const float* __restrict__ g1wT, const float* __restrict__ g1b,
    const float* __restrict__ g2wT, const float* __restrict__ g2b,
    unsigned short* __restrict__ SWb) {
  __shared__ float gf2t[128 * 64];
  __shared__ float ht[32 * 64];
  const int b = blockIdx.x >> 6;
  const int i0 = (blockIdx.x & 63) << 6;
  const int t = threadIdx.x;
  const int pos = t & 63, g = t >> 6;
  const int i = i0 + pos;

  float lp4[4], lsum = 0.f;
  #pragma unroll
  for (int p = 0; p < 4; p++) { lp4[p] = Lp[((p * 8 + b) << 12) + i]; lsum += lp4[p]; }
  float o[64];
  #pragma unroll
  for (int k = 0; k < 64; k++) o[k] = 0.f;
  #pragma unroll
  for (int p = 0; p < 4; p++) {
    float w = lp4[p] / lsum;
    const uint2* prow = (const uint2*)&Op[(((p * 8 + b) << 12) + i) << 6];
    #pragma unroll
    for (int k = 0; k < 16; k++) {
      uint2 u = prow[k];
      o[k * 4 + 0] += w * __uint_as_float(u.x << 16);
      o[k * 4 + 1] += w * __uint_as_float(u.x & 0xFFFF0000u);
      o[k * 4 + 2] += w * __uint_as_float(u.y << 16);
      o[k * 4 + 3] += w * __uint_as_float(u.y & 0xFFFF0000u);
    }
  }

  #pragma unroll 1
  for (int jc = 0; jc < 4; jc++) {
    #pragma unroll
    for (int j = 0; j < 8; j++) {
      const int oc = g * 32 + jc * 8 + j;
      const float4* w = (const float4*)&ow[oc << 6];
      float a = obias[oc];
      #pragma unroll
      for (int k = 0; k < 16; k++) {
        float4 wk = w[k];
        a += wk.x * o[k * 4] + wk.y * o[k * 4 + 1] + wk.z * o[k * 4 + 2] + wk.w * o[k * 4 + 3];
      }
      gf2t[oc * 64 + pos] = a;
    }
  }
  __syncthreads();

  {
    float a8[8];
    #pragma unroll
    for (int j = 0; j < 8; j++) a8[j] = g1b[g * 8 + j];
    #pragma unroll 4
    for (int c = 0; c < 128; c++) {
      float v = gf2t[c * 64 + pos];
      float4 w0 = *(const float4*)&g1wT[(c << 5) + g * 8];
      float4 w1 = *(const float4*)&g1wT[(c << 5) + g * 8 + 4];
      a8[0] += w0.x * v; a8[1] += w0.y * v; a8[2] += w0.z * v; a8[3] += w0.w * v;
      a8[4] += w1.x * v; a8[5] += w1.y * v; a8[6] += w1.z * v; a8[7] += w1.w * v;
    }
    #pragma unroll
    for (int j = 0; j < 8; j++) ht[(g * 8 + j) * 64 + pos] = fmaxf(a8[j], 0.f);
  }
  __syncthreads();

  #pragma unroll 1
  for (int jc = 0; jc < 4; jc++) {
    float a8[8];
    #pragma unroll
    for (int j = 0; j < 8; j++) a8[j] = g2b[g * 32 + jc * 8 + j];
    #pragma unroll 4
    for (int c = 0; c < 32; c++) {
      float v = ht[c * 64 + pos];
      float4 w0 = *(const float4*)&g2wT[(c << 7) + g * 32 + jc * 8];
      float4 w1 = *(const float4*)&g2wT[(c << 7) + g * 32 + jc * 8 + 4];
      a8[0] += w0.x * v; a8[1] += w0.y * v; a8[2] += w0.z * v; a8[3] += w0.w * v;
      a8[4] += w1.x * v; a8[5] += w1.y * v; a8[6] += w1.z * v; a8[7] += w1.w * v;
    }
    #pragma unroll
    for (int j = 0; j < 8; j++) {
      float s = 1.0f / (1.0f + exp2f(-LOG2E * a8[j]));
      SWb[(((b * 128 + g * 32 + jc * 8 + j)) << 12) + i] = (unsigned short)f2bf(s);
    }
  }
}

// ---------------------------------------------------------------------------
// K4: gated outputs: x1*(1+w1), x_k*(1+downsample(w_k)). SW is bf16.
// ---------------------------------------------------------------------------
__device__ __forceinline__ float bilin64(const unsigned short* __restrict__ p,
                                         int oy, int ox, int n) {
  float yf = (float)oy * 63.0f / (float)n;
  int y0 = (int)yf; if (y0 > 63) y0 = 63;
  int y1 = y0 + 1;  if (y1 > 63) y1 = 63;
  float wy = yf - (float)y0;
  float xf = (float)ox * 63.0f / (float)n;
  int x0 = (int)xf; if (x0 > 63) x0 = 63;
  int x1 = x0 + 1;  if (x1 > 63) x1 = 63;
  float wx = xf - (float)x0;
  float v00 = bf2f(p[y0 * 64 + x0]), v01 = bf2f(p[y0 * 64 + x1]);
  float v10 = bf2f(p[y1 * 64 + x0]), v11 = bf2f(p[y1 * 64 + x1]);
  float top = v00 + wx * (v01 - v00);
  float bot = v10 + wx * (v11 - v10);
  return top + wy * (bot - top);
}

__global__ __launch_bounds__(256) void k_final(
    const float* __restrict__ x1, const float* __restrict__ x2,
    const float* __restrict__ x3, const float* __restrict__ x4,
    const unsigned short* __restrict__ SWb, float* __restrict__ out) {
  const int N1 = 1048576, N2 = 262144, N3 = 65536, N4 = 16384;
  int idx = blockIdx.x * 256 + threadIdx.x;
  if (idx < N1) {
    int b = idx >> 17, rr = idx & 131071;
    int c = rr >> 12, hw = rr & 4095;
    out[idx] = x1[idx] * (1.f + bf2f(SWb[((b * 128 + c) << 12) + hw]));
  } else if (idx < N1 + N2) {
    int i2 = idx - N1;
    int b = i2 >> 15, rr = i2 & 32767;
    int c = rr >> 10, oy = (rr >> 5) & 31, ox = rr & 31;
    float w = bilin64(SWb + ((b * 128 + 32 + c) << 12), oy, ox, 31);
    out[idx] = x2[i2] * (1.f + w);
  } else if (idx < N1 + N2 + N3) {
    int i3 = idx - N1 - N2;
    int b = i3 >> 13, rr = i3 & 8191;
    int c = rr >> 8, oy = (rr >> 4) & 15, ox = rr & 15;
    float w = bilin64(SWb + ((b * 128 + 64 + c) << 12), oy, ox, 15);
    out[idx] = x3[i3] * (1.f + w);
  } else if (idx < N1 + N2 + N3 + N4) {
    int i4 = idx - N1 - N2 - N3;
    int b = i4 >> 11, rr = i4 & 2047;
    int c = rr >> 6, oy = (rr >> 3) & 7, ox = rr & 7;
    float w = bilin64(SWb + ((b * 128 + 96 + c) << 12), oy, ox, 7);
    out[idx] = x4[i4] * (1.f + w);
  }
}

// ---------------------------------------------------------------------------
extern "C" void kernel_launch(void* const* d_in, const int* in_sizes, int n_in,
                              void* d_out, int out_size, void* d_ws, size_t ws_size,
                              hipStream_t stream) {
  const float* x1  = (const float*)d_in[0];
  const float* x2  = (const float*)d_in[1];
  const float* x3  = (const float*)d_in[2];
  const float* x4  = (const float*)d_in[3];
  const float* qw  = (const float*)d_in[4];
  const float* qb  = (const float*)d_in[5];
  const float* kw  = (const float*)d_in[6];
  const float* kb  = (const float*)d_in[7];
  const float* vw  = (const float*)d_in[8];
  const float* vb  = (const float*)d_in[9];
  const float* ow  = (const float*)d_in[10];
  const float* ob  = (const float*)d_in[11];
  const float* g1w = (const float*)d_in[12];
  const float* g1b = (const float*)d_in[13];
  const float* g2w = (const float*)d_in[14];
  const float* g2b = (const float*)d_in[15];
  float* out = (float*)d_out;

  char* ws = (char*)d_ws;
  unsigned short* Qg  = (unsigned short*)(ws + 0);
  unsigned short* Kg  = (unsigned short*)(ws + 4194304);
  unsigned short* Vg  = (unsigned short*)(ws + 8388608);
  unsigned short* SWb = (unsigned short*)(ws + 0);          // aliases Q/K (dead)
  unsigned short* Op  = (unsigned short*)(ws + 12582912);
  float* Lp   = (float*)(ws + 29360128);
  unsigned short* WTb = (unsigned short*)(ws + 29884416);
  float* bqkv = (float*)(ws + 29933568);
  float* g1wT = (float*)(ws + 29934592);
  float* g2wT = (float*)(ws + 29950976);

  k_prep<<<96, 256, 0, stream>>>(qw, qb, kw, kb, vw, vb, g1w, g2w,
                                 WTb, bqkv, g1wT, g2wT);
  k_qkv<<<256, 256, 0, stream>>>(x1, x2, x3, x4, WTb, bqkv, Qg, Kg, Vg);
  k_attn<<<1024, 256, 0, stream>>>(Qg, Kg, Vg, Op, Lp);
  k_out<<<512, 256, 0, stream>>>(Op, Lp, ow, ob, g1wT, g1b, g2wT, g2b, SWb);
  k_final<<<5440, 256, 0, stream>>>(x1, x2, x3, x4, SWb, out);
}

// Round 4
// 201.656 us; speedup vs baseline: 2.0008x; 1.3245x over previous
//
#include <hip/hip_runtime.h>
#include <hip/hip_bf16.h>

// ---------------------------------------------------------------------------
// DynamicFeaturePyramid forward, MI355X.
// attention: B=8, S=4096, D=64 single head; flash-fused bf16 MFMA,
// key-split x4 (no-max softmax -> partials combine by plain weighted sum).
// k_qkv and k_out are MFMA GEMMs.
// Workspace (bytes):
//   Q   (b,i,c) bf16  :        0 ..  4194304   } phase 1
//   K   (b,j,c) bf16  :  4194304 ..  8388608   }
//   Vt  (b,c,j) bf16  :  8388608 .. 12582912   }
//   SWb (b,c,i) bf16  :        0 ..  8388608   } phase 2 (aliases Q/K, dead)
//   Op  (p,b,i,c)bf16 : 12582912 .. 29360128   (per-part normalized O)
//   Lp  (p,b,i) fp32  : 29360128 .. 29884416
//   WTb (oc,c)  bf16  : 29884416 .. 29933568   (192x128, q rows *log2e)
//   bqkv(192)   fp32  : 29933568 .. 29934336 (pad 29934592)
//   owb (128,64)bf16  : 29934592 .. 29950976
//   g1wb(32,128)bf16  : 29950976 .. 29959168
//   g2wb(128,32)bf16  : 29959168 .. 29967360
// ---------------------------------------------------------------------------

typedef __attribute__((ext_vector_type(8))) short s16x8;   // 8 bf16 = 4 VGPRs
typedef __attribute__((ext_vector_type(4))) float f32x4;   // MFMA C/D frag

#define LOG2E 1.44269504088896340736f

__device__ __forceinline__ unsigned int f2bf(float f) {
    unsigned int u = __float_as_uint(f);
    u += 0x7fffu + ((u >> 16) & 1u);   // RNE (inputs finite)
    return u >> 16;
}
__device__ __forceinline__ unsigned int pk2bf(float a, float b) {
    union { __hip_bfloat162 h; unsigned int u; } cv;
    cv.h = __float22bfloat162_rn(make_float2(a, b));   // v_cvt_pk_bf16_f32
    return cv.u;
}
__device__ __forceinline__ float bf2f(unsigned short u) {
    return __uint_as_float((unsigned int)u << 16);
}

// ---------------------------------------------------------------------------
// K0: weight prep. WTb[oc][c] bf16 (q rows *log2e), bias fp32, and straight
// bf16 casts of ow/g1w/g2w (already [oc][c] row-major).
// ---------------------------------------------------------------------------
__global__ __launch_bounds__(256) void k_prep(
    const float* __restrict__ qw, const float* __restrict__ qb,
    const float* __restrict__ kw, const float* __restrict__ kb,
    const float* __restrict__ vw, const float* __restrict__ vb,
    const float* __restrict__ ow, const float* __restrict__ g1w,
    const float* __restrict__ g2w,
    unsigned short* __restrict__ WTb, float* __restrict__ bqkv,
    unsigned short* __restrict__ owb, unsigned short* __restrict__ g1wb,
    unsigned short* __restrict__ g2wb) {
  int t = blockIdx.x * 256 + threadIdx.x;
  if (t < 192 * 128) {            // WTb[oc][c]
    int oc = t >> 7, c = t & 127;
    float v;
    if (oc < 64)       v = qw[oc * 128 + c] * LOG2E;
    else if (oc < 128) v = kw[(oc - 64) * 128 + c];
    else               v = vw[(oc - 128) * 128 + c];
    WTb[t] = (unsigned short)f2bf(v);
  }
  if (t < 192) {
    float v;
    if (t < 64)       v = qb[t] * LOG2E;
    else if (t < 128) v = kb[t - 64];
    else              v = vb[t - 128];
    bqkv[t] = v;
  }
  if (t < 128 * 64) g1wb[t & 4095] = (unsigned short)f2bf(g1w[t & 4095]);  // 4096
  if (t < 128 * 64) owb[t] = (unsigned short)f2bf(ow[t]);                  // 8192
  if (t < 128 * 32) g2wb[t] = (unsigned short)f2bf(g2w[t]);                // 4096
}

// ---------------------------------------------------------------------------
// K1: fused (bilinear-upsample + concat) -> gf bf16 tile [pos][c] in LDS ->
// MFMA QKV projection. Block: (b, 128 pos); grid 8*32=256.
// ---------------------------------------------------------------------------
__global__ __launch_bounds__(256) void k_qkv(
    const float* __restrict__ x1, const float* __restrict__ x2,
    const float* __restrict__ x3, const float* __restrict__ x4,
    const unsigned short* __restrict__ WTb, const float* __restrict__ bqkv,
    unsigned short* __restrict__ Qg, unsigned short* __restrict__ Kg,
    unsigned short* __restrict__ Vg) {
  __shared__ __align__(16) unsigned short gfb[128 * 136];   // [pos][c] stride 136
  unsigned int* gfbu = (unsigned int*)gfb;                  // word idx = pos*68 + cp

  const int b = blockIdx.x >> 5;
  const int i0 = (blockIdx.x & 31) << 7;
  const int t = threadIdx.x;

  {
    const int cp = t >> 2, q = t & 3;
    const int c0 = cp << 1;
    const int pbase = q << 5;
    const int oy = (i0 >> 6) + (q >> 1);
    const int ox0 = (q & 1) << 5;

    if (cp < 16) {
      const float* s0 = x1 + (((b * 32 + c0) << 12) + (oy << 6) + ox0);
      const float* s1 = s0 + 4096;
      #pragma unroll
      for (int k8 = 0; k8 < 8; k8++) {
        float4 va = ((const float4*)s0)[k8];
        float4 vb = ((const float4*)s1)[k8];
        int p = pbase + k8 * 4;
        gfbu[(p + 0) * 68 + cp] = pk2bf(va.x, vb.x);
        gfbu[(p + 1) * 68 + cp] = pk2bf(va.y, vb.y);
        gfbu[(p + 2) * 68 + cp] = pk2bf(va.z, vb.z);
        gfbu[(p + 3) * 68 + cp] = pk2bf(va.w, vb.w);
      }
    } else {
      const float* base; int S, cs;
      if (cp < 32)      { base = x2; S = 32; cs = c0 - 32; }
      else if (cp < 48) { base = x3; S = 16; cs = c0 - 64; }
      else              { base = x4; S = 8;  cs = c0 - 96; }
      const float* pl0 = base + (b * 32 + cs) * S * S;
      const float* pl1 = pl0 + S * S;
      float yf = (float)oy * (float)(S - 1) * (1.0f / 63.0f);
      int y0 = (int)yf; if (y0 > S - 1) y0 = S - 1;
      int y1 = y0 + 1;  if (y1 > S - 1) y1 = S - 1;
      float wy = yf - (float)y0;
      const float* r00 = pl0 + y0 * S; const float* r01 = pl0 + y1 * S;
      const float* r10 = pl1 + y0 * S; const float* r11 = pl1 + y1 * S;
      for (int k = 0; k < 32; k++) {
        int ox = ox0 + k;
        float xf = (float)ox * (float)(S - 1) * (1.0f / 63.0f);
        int xx0 = (int)xf; if (xx0 > S - 1) xx0 = S - 1;
        int xx1 = xx0 + 1; if (xx1 > S - 1) xx1 = S - 1;
        float wx = xf - (float)xx0;
        float a0 = r00[xx0] + wx * (r00[xx1] - r00[xx0]);
        float b0 = r01[xx0] + wx * (r01[xx1] - r01[xx0]);
        float v0 = a0 + wy * (b0 - a0);
        float a1 = r10[xx0] + wx * (r10[xx1] - r10[xx0]);
        float b1 = r11[xx0] + wx * (r11[xx1] - r11[xx0]);
        float v1 = a1 + wy * (b1 - a1);
        gfbu[(pbase + k) * 68 + cp] = pk2bf(v0, v1);
      }
    }
  }
  __syncthreads();

  const int wv = t >> 6, lane = t & 63;
  const int r = lane & 15, qd = lane >> 4;
  const int ocb = wv * 48;

  s16x8 af[3][4];
  #pragma unroll
  for (int mti = 0; mti < 3; mti++)
    #pragma unroll
    for (int ks = 0; ks < 4; ks++)
      af[mti][ks] = *(const s16x8*)&WTb[(ocb + mti * 16 + r) * 128 + ks * 32 + qd * 8];
  float4 bias[3];
  #pragma unroll
  for (int mti = 0; mti < 3; mti++)
    bias[mti] = *(const float4*)&bqkv[ocb + mti * 16 + qd * 4];

  f32x4 zf = {0.f, 0.f, 0.f, 0.f};
  #pragma unroll 1
  for (int nt = 0; nt < 8; nt++) {
    s16x8 bfr[4];
    #pragma unroll
    for (int ks = 0; ks < 4; ks++)
      bfr[ks] = *(const s16x8*)&gfb[(nt * 16 + r) * 136 + ks * 32 + qd * 8];
    f32x4 acc[3] = {zf, zf, zf};
    #pragma unroll
    for (int ks = 0; ks < 4; ks++)
      #pragma unroll
      for (int mti = 0; mti < 3; mti++)
        acc[mti] = __builtin_amdgcn_mfma_f32_16x16x32_bf16(af[mti][ks], bfr[ks], acc[mti], 0, 0, 0);

    const int pos = i0 + nt * 16 + r;
    #pragma unroll
    for (int mti = 0; mti < 3; mti++) {
      const int gmt = wv * 3 + mti;
      float ax = acc[mti].x + bias[mti].x;
      float ay = acc[mti].y + bias[mti].y;
      float az = acc[mti].z + bias[mti].z;
      float aw = acc[mti].w + bias[mti].w;
      if (gmt < 4) {
        uint2 w; w.x = pk2bf(ax, ay); w.y = pk2bf(az, aw);
        *(uint2*)&Qg[(((b << 12) + pos) << 6) + gmt * 16 + qd * 4] = w;
      } else if (gmt < 8) {
        uint2 w; w.x = pk2bf(ax, ay); w.y = pk2bf(az, aw);
        *(uint2*)&Kg[(((b << 12) + pos) << 6) + (gmt - 4) * 16 + qd * 4] = w;
      } else {
        int ocv = (gmt - 8) * 16 + qd * 4;
        Vg[((b * 64 + ocv + 0) << 12) + pos] = (unsigned short)f2bf(ax);
        Vg[((b * 64 + ocv + 1) << 12) + pos] = (unsigned short)f2bf(ay);
        Vg[((b * 64 + ocv + 2) << 12) + pos] = (unsigned short)f2bf(az);
        Vg[((b * 64 + ocv + 3) << 12) + pos] = (unsigned short)f2bf(aw);
      }
    }
  }
}

// ---------------------------------------------------------------------------
// K2: flash attention, transposed (S^T = K*Q^T, O^T = V^T*P^T), key-split x4.
// ---------------------------------------------------------------------------
__global__ __launch_bounds__(256, 4) void k_attn(
    const unsigned short* __restrict__ Qg, const unsigned short* __restrict__ Kg,
    const unsigned short* __restrict__ Vg, unsigned short* __restrict__ Op,
    float* __restrict__ Lp) {
  __shared__ __align__(16) unsigned short Kl[64 * 72];
  __shared__ __align__(16) unsigned short Vl[64 * 72];
  __shared__ __align__(16) unsigned short Pl[4][32 * 72];

  const int b = blockIdx.x >> 7;
  const int part = (blockIdx.x >> 5) & 3;
  const int qg = blockIdx.x & 31;
  const int i0 = qg << 7;
  const int t = threadIdx.x;
  const int wv = t >> 6, lane = t & 63;
  const int r = lane & 15, qd = lane >> 4;
  const int qbase = i0 + wv * 32;

  s16x8 qf[2][2];
  #pragma unroll
  for (int nt = 0; nt < 2; nt++)
    #pragma unroll
    for (int ks = 0; ks < 2; ks++)
      qf[nt][ks] = *(const s16x8*)&Qg[(((b << 12) + qbase + nt * 16 + r) << 6) + ks * 32 + qd * 8];

  f32x4 zf = {0.f, 0.f, 0.f, 0.f};
  f32x4 acc[2][4];
  #pragma unroll
  for (int nt = 0; nt < 2; nt++)
    #pragma unroll
    for (int mt = 0; mt < 4; mt++) acc[nt][mt] = zf;
  float l[2] = {0.f, 0.f};

  const int srow = t >> 3, sseg = t & 7;
  const unsigned short* kt0 = &Kg[(((b << 12) + (part << 10) + srow) << 6) + sseg * 8];
  const unsigned short* vt0 = &Vg[((b * 64 + srow) << 12) + (part << 10) + sseg * 8];
  uint4 pk0 = *(const uint4*)(kt0);
  uint4 pk1 = *(const uint4*)(kt0 + (32 << 6));
  uint4 pv0 = *(const uint4*)(vt0);
  uint4 pv1 = *(const uint4*)(vt0 + (32 << 12));

  for (int it = 0; it < 16; it++) {
    __syncthreads();
    *(uint4*)&Kl[srow * 72 + sseg * 8] = pk0;
    *(uint4*)&Kl[(srow + 32) * 72 + sseg * 8] = pk1;
    *(uint4*)&Vl[srow * 72 + sseg * 8] = pv0;
    *(uint4*)&Vl[(srow + 32) * 72 + sseg * 8] = pv1;
    __syncthreads();
    if (it < 15) {
      int j0 = (it + 1) << 6;
      pk0 = *(const uint4*)(kt0 + (j0 << 6));
      pk1 = *(const uint4*)(kt0 + ((j0 + 32) << 6));
      pv0 = *(const uint4*)(vt0 + j0);
      pv1 = *(const uint4*)(vt0 + (32 << 12) + j0);
    }

    f32x4 st[4][2];
    #pragma unroll
    for (int mt = 0; mt < 4; mt++) {
      s16x8 kf0 = *(const s16x8*)&Kl[(mt * 16 + r) * 72 + qd * 8];
      s16x8 kf1 = *(const s16x8*)&Kl[(mt * 16 + r) * 72 + 32 + qd * 8];
      #pragma unroll
      for (int nt = 0; nt < 2; nt++) {
        f32x4 s = __builtin_amdgcn_mfma_f32_16x16x32_bf16(kf0, qf[nt][0], zf, 0, 0, 0);
        s = __builtin_amdgcn_mfma_f32_16x16x32_bf16(kf1, qf[nt][1], s, 0, 0, 0);
        st[mt][nt] = s;
      }
    }

    #pragma unroll
    for (int nt = 0; nt < 2; nt++) {
      float rs = 0.f;
      #pragma unroll
      for (int mt = 0; mt < 4; mt++) {
        float px = exp2f(fminf(st[mt][nt].x, 80.f));
        float py = exp2f(fminf(st[mt][nt].y, 80.f));
        float pz = exp2f(fminf(st[mt][nt].z, 80.f));
        float pw = exp2f(fminf(st[mt][nt].w, 80.f));
        rs += (px + py) + (pz + pw);
        uint2 w;
        w.x = pk2bf(px, py);
        w.y = pk2bf(pz, pw);
        *(uint2*)&Pl[wv][(nt * 16 + r) * 72 + mt * 16 + qd * 4] = w;
      }
      rs += __shfl_xor(rs, 16);
      rs += __shfl_xor(rs, 32);
      l[nt] += rs;
    }
    __builtin_amdgcn_wave_barrier();

    #pragma unroll
    for (int ks = 0; ks < 2; ks++) {
      s16x8 pf0 = *(const s16x8*)&Pl[wv][(r) * 72 + ks * 32 + qd * 8];
      s16x8 pf1 = *(const s16x8*)&Pl[wv][(16 + r) * 72 + ks * 32 + qd * 8];
      #pragma unroll
      for (int mt = 0; mt < 4; mt++) {
        s16x8 vf = *(const s16x8*)&Vl[(mt * 16 + r) * 72 + ks * 32 + qd * 8];
        acc[0][mt] = __builtin_amdgcn_mfma_f32_16x16x32_bf16(vf, pf0, acc[0][mt], 0, 0, 0);
        acc[1][mt] = __builtin_amdgcn_mfma_f32_16x16x32_bf16(vf, pf1, acc[1][mt], 0, 0, 0);
      }
    }
  }

  #pragma unroll
  for (int nt = 0; nt < 2; nt++) {
    float inv = 1.0f / l[nt];
    int qrow = qbase + nt * 16 + r;
    unsigned short* orow = &Op[(((part * 8 + b) << 12) + qrow) << 6];
    #pragma unroll
    for (int mt = 0; mt < 4; mt++) {
      uint2 w;
      w.x = pk2bf(acc[nt][mt].x * inv, acc[nt][mt].y * inv);
      w.y = pk2bf(acc[nt][mt].z * inv, acc[nt][mt].w * inv);
      *(uint2*)&orow[mt * 16 + qd * 4] = w;
    }
    if (qd == 0) Lp[((part * 8 + b) << 12) + qrow] = l[nt];
  }
}

// ---------------------------------------------------------------------------
// K3: MFMA version. combine partials -> Ot[pos][c] (LDS) -> GEMM1 (ow) ->
// gf2t[pos][oc] -> GEMM2 (g1,relu) -> ht[pos][oc2] -> GEMM3 swapped (g2,
// sigmoid) -> SWb direct uint2 stores. Block: (b, 128 pos); grid 256.
// ---------------------------------------------------------------------------
__global__ __launch_bounds__(256) void k_out(
    const unsigned short* __restrict__ Op, const float* __restrict__ Lp,
    const unsigned short* __restrict__ owb, const float* __restrict__ obias,
    const unsigned short* __restrict__ g1wb, const float* __restrict__ g1b,
    const unsigned short* __restrict__ g2wb, const float* __restrict__ g2b,
    unsigned short* __restrict__ SWb) {
  __shared__ __align__(16) unsigned short Ot[128 * 72];     // [pos][c] c<64
  __shared__ __align__(16) unsigned short gf2t[128 * 136];  // [pos][oc] oc<128
  __shared__ __align__(16) unsigned short ht[128 * 40];     // [pos][oc2] oc2<32
  const int b = blockIdx.x >> 5;
  const int i0 = (blockIdx.x & 31) << 7;
  const int t = threadIdx.x;

  // ---- combine partials: Ot[pos][c] = sum_p (l_p/lsum) * Op[p] ----
  {
    const int pos = t >> 1, half = t & 1;
    const int i = i0 + pos;
    float lp4[4], lsum = 0.f;
    #pragma unroll
    for (int p = 0; p < 4; p++) { lp4[p] = Lp[((p * 8 + b) << 12) + i]; lsum += lp4[p]; }
    float o[32];
    #pragma unroll
    for (int k = 0; k < 32; k++) o[k] = 0.f;
    #pragma unroll
    for (int p = 0; p < 4; p++) {
      float w = lp4[p] / lsum;
      const uint2* prow = (const uint2*)&Op[((((p * 8 + b) << 12) + i) << 6) + half * 32];
      #pragma unroll
      for (int k = 0; k < 8; k++) {
        uint2 u = prow[k];
        o[k * 4 + 0] += w * __uint_as_float(u.x << 16);
        o[k * 4 + 1] += w * __uint_as_float(u.x & 0xFFFF0000u);
        o[k * 4 + 2] += w * __uint_as_float(u.y << 16);
        o[k * 4 + 3] += w * __uint_as_float(u.y & 0xFFFF0000u);
      }
    }
    unsigned int* dst = (unsigned int*)&Ot[pos * 72 + half * 32];
    #pragma unroll
    for (int k = 0; k < 16; k++) dst[k] = pk2bf(o[2 * k], o[2 * k + 1]);
  }
  __syncthreads();

  const int wv = t >> 6, lane = t & 63;
  const int r = lane & 15, qd = lane >> 4;
  f32x4 zf = {0.f, 0.f, 0.f, 0.f};

  // ---- GEMM1: gf2[oc=128][pos=128] = owb(128x64) * Ot^T; wave -> 32 oc ----
  {
    const int ocb = wv * 32;
    s16x8 af[2][2];
    #pragma unroll
    for (int mt = 0; mt < 2; mt++)
      #pragma unroll
      for (int ks = 0; ks < 2; ks++)
        af[mt][ks] = *(const s16x8*)&owb[(ocb + mt * 16 + r) * 64 + ks * 32 + qd * 8];
    float4 bias[2];
    #pragma unroll
    for (int mt = 0; mt < 2; mt++)
      bias[mt] = *(const float4*)&obias[ocb + mt * 16 + qd * 4];
    #pragma unroll 1
    for (int nt = 0; nt < 8; nt++) {
      s16x8 bfr[2];
      #pragma unroll
      for (int ks = 0; ks < 2; ks++)
        bfr[ks] = *(const s16x8*)&Ot[(nt * 16 + r) * 72 + ks * 32 + qd * 8];
      f32x4 acc[2] = {zf, zf};
      #pragma unroll
      for (int ks = 0; ks < 2; ks++)
        #pragma unroll
        for (int mt = 0; mt < 2; mt++)
          acc[mt] = __builtin_amdgcn_mfma_f32_16x16x32_bf16(af[mt][ks], bfr[ks], acc[mt], 0, 0, 0);
      #pragma unroll
      for (int mt = 0; mt < 2; mt++) {
        uint2 w;
        w.x = pk2bf(acc[mt].x + bias[mt].x, acc[mt].y + bias[mt].y);
        w.y = pk2bf(acc[mt].z + bias[mt].z, acc[mt].w + bias[mt].w);
        *(uint2*)&gf2t[(nt * 16 + r) * 136 + ocb + mt * 16 + qd * 4] = w;
      }
    }
  }
  __syncthreads();

  // ---- GEMM2: h[oc2=32][pos] = g1wb(32x128) * gf2t^T; wave -> 32 pos ----
  {
    s16x8 af[2][4];
    #pragma unroll
    for (int mt = 0; mt < 2; mt++)
      #pragma unroll
      for (int ks = 0; ks < 4; ks++)
        af[mt][ks] = *(const s16x8*)&g1wb[(mt * 16 + r) * 128 + ks * 32 + qd * 8];
    float4 bias[2];
    #pragma unroll
    for (int mt = 0; mt < 2; mt++)
      bias[mt] = *(const float4*)&g1b[mt * 16 + qd * 4];
    #pragma unroll
    for (int nt = 0; nt < 2; nt++) {
      const int pn = (wv * 2 + nt) * 16 + r;
      s16x8 bfr[4];
      #pragma unroll
      for (int ks = 0; ks < 4; ks++)
        bfr[ks] = *(const s16x8*)&gf2t[pn * 136 + ks * 32 + qd * 8];
      f32x4 acc[2] = {zf, zf};
      #pragma unroll
      for (int ks = 0; ks < 4; ks++)
        #pragma unroll
        for (int mt = 0; mt < 2; mt++)
          acc[mt] = __builtin_amdgcn_mfma_f32_16x16x32_bf16(af[mt][ks], bfr[ks], acc[mt], 0, 0, 0);
      #pragma unroll
      for (int mt = 0; mt < 2; mt++) {
        uint2 w;
        w.x = pk2bf(fmaxf(acc[mt].x + bias[mt].x, 0.f), fmaxf(acc[mt].y + bias[mt].y, 0.f));
        w.y = pk2bf(fmaxf(acc[mt].z + bias[mt].z, 0.f), fmaxf(acc[mt].w + bias[mt].w, 0.f));
        *(uint2*)&ht[pn * 40 + mt * 16 + qd * 4] = w;
      }
    }
  }
  __syncthreads();

  // ---- GEMM3 (swapped): sw[pos][oc3] = ht(pos x 32) * g2wb^T; K=32 ----
  // m=pos (8 tiles), n=oc3 (wave -> 32 oc3), D rows = 4 consecutive pos.
  {
    const int nb = wv * 32;
    s16x8 bfg[2];
    float bias[2];
    #pragma unroll
    for (int ntl = 0; ntl < 2; ntl++) {
      bfg[ntl] = *(const s16x8*)&g2wb[(nb + ntl * 16 + r) * 32 + qd * 8];
      bias[ntl] = g2b[nb + ntl * 16 + r];
    }
    #pragma unroll 1
    for (int mt = 0; mt < 8; mt++) {
      s16x8 af = *(const s16x8*)&ht[(mt * 16 + r) * 40 + qd * 8];
      #pragma unroll
      for (int ntl = 0; ntl < 2; ntl++) {
        f32x4 acc = __builtin_amdgcn_mfma_f32_16x16x32_bf16(af, bfg[ntl], zf, 0, 0, 0);
        const int oc3 = nb + ntl * 16 + r;
        float s0 = 1.0f / (1.0f + exp2f(-LOG2E * (acc.x + bias[ntl])));
        float s1 = 1.0f / (1.0f + exp2f(-LOG2E * (acc.y + bias[ntl])));
        float s2 = 1.0f / (1.0f + exp2f(-LOG2E * (acc.z + bias[ntl])));
        float s3 = 1.0f / (1.0f + exp2f(-LOG2E * (acc.w + bias[ntl])));
        uint2 w; w.x = pk2bf(s0, s1); w.y = pk2bf(s2, s3);
        *(uint2*)&SWb[((b * 128 + oc3) << 12) + i0 + mt * 16 + qd * 4] = w;
      }
    }
  }
}

// ---------------------------------------------------------------------------
// K4: gated outputs: x1*(1+w1), x_k*(1+downsample(w_k)). SW is bf16.
// ---------------------------------------------------------------------------
__device__ __forceinline__ float bilin64(const unsigned short* __restrict__ p,
                                         int oy, int ox, int n) {
  float yf = (float)oy * 63.0f / (float)n;
  int y0 = (int)yf; if (y0 > 63) y0 = 63;
  int y1 = y0 + 1;  if (y1 > 63) y1 = 63;
  float wy = yf - (float)y0;
  float xf = (float)ox * 63.0f / (float)n;
  int x0 = (int)xf; if (x0 > 63) x0 = 63;
  int x1 = x0 + 1;  if (x1 > 63) x1 = 63;
  float wx = xf - (float)x0;
  float v00 = bf2f(p[y0 * 64 + x0]), v01 = bf2f(p[y0 * 64 + x1]);
  float v10 = bf2f(p[y1 * 64 + x0]), v11 = bf2f(p[y1 * 64 + x1]);
  float top = v00 + wx * (v01 - v00);
  float bot = v10 + wx * (v11 - v10);
  return top + wy * (bot - top);
}

__global__ __launch_bounds__(256) void k_final(
    const float* __restrict__ x1, const float* __restrict__ x2,
    const float* __restrict__ x3, const float* __restrict__ x4,
    const unsigned short* __restrict__ SWb, float* __restrict__ out) {
  const int N1 = 1048576, N2 = 262144, N3 = 65536, N4 = 16384;
  int idx = blockIdx.x * 256 + threadIdx.x;
  if (idx < N1) {
    int b = idx >> 17, rr = idx & 131071;
    int c = rr >> 12, hw = rr & 4095;
    out[idx] = x1[idx] * (1.f + bf2f(SWb[((b * 128 + c) << 12) + hw]));
  } else if (idx < N1 + N2) {
    int i2 = idx - N1;
    int b = i2 >> 15, rr = i2 & 32767;
    int c = rr >> 10, oy = (rr >> 5) & 31, ox = rr & 31;
    float w = bilin64(SWb + ((b * 128 + 32 + c) << 12), oy, ox, 31);
    out[idx] = x2[i2] * (1.f + w);
  } else if (idx < N1 + N2 + N3) {
    int i3 = idx - N1 - N2;
    int b = i3 >> 13, rr = i3 & 8191;
    int c = rr >> 8, oy = (rr >> 4) & 15, ox = rr & 15;
    float w = bilin64(SWb + ((b * 128 + 64 + c) << 12), oy, ox, 15);
    out[idx] = x3[i3] * (1.f + w);
  } else if (idx < N1 + N2 + N3 + N4) {
    int i4 = idx - N1 - N2 - N3;
    int b = i4 >> 11, rr = i4 & 2047;
    int c = rr >> 6, oy = (rr >> 3) & 7, ox = rr & 7;
    float w = bilin64(SWb + ((b * 128 + 96 + c) << 12), oy, ox, 7);
    out[idx] = x4[i4] * (1.f + w);
  }
}

// ---------------------------------------------------------------------------
extern "C" void kernel_launch(void* const* d_in, const int* in_sizes, int n_in,
                              void* d_out, int out_size, void* d_ws, size_t ws_size,
                              hipStream_t stream) {
  const float* x1  = (const float*)d_in[0];
  const float* x2  = (const float*)d_in[1];
  const float* x3  = (const float*)d_in[2];
  const float* x4  = (const float*)d_in[3];
  const float* qw  = (const float*)d_in[4];
  const float* qb  = (const float*)d_in[5];
  const float* kw  = (const float*)d_in[6];
  const float* kb  = (const float*)d_in[7];
  const float* vw  = (const float*)d_in[8];
  const float* vb  = (const float*)d_in[9];
  const float* ow  = (const float*)d_in[10];
  const float* ob  = (const float*)d_in[11];
  const float* g1w = (const float*)d_in[12];
  const float* g1b = (const float*)d_in[13];
  const float* g2w = (const float*)d_in[14];
  const float* g2b = (const float*)d_in[15];
  float* out = (float*)d_out;

  char* ws = (char*)d_ws;
  unsigned short* Qg  = (unsigned short*)(ws + 0);
  unsigned short* Kg  = (unsigned short*)(ws + 4194304);
  unsigned short* Vg  = (unsigned short*)(ws + 8388608);
  unsigned short* SWb = (unsigned short*)(ws + 0);          // aliases Q/K (dead)
  unsigned short* Op  = (unsigned short*)(ws + 12582912);
  float* Lp   = (float*)(ws + 29360128);
  unsigned short* WTb = (unsigned short*)(ws + 29884416);
  float* bqkv = (float*)(ws + 29933568);
  unsigned short* owb  = (unsigned short*)(ws + 29934592);
  unsigned short* g1wb = (unsigned short*)(ws + 29950976);
  unsigned short* g2wb = (unsigned short*)(ws + 29959168);

  k_prep<<<96, 256, 0, stream>>>(qw, qb, kw, kb, vw, vb, ow, g1w, g2w,
                                 WTb, bqkv, owb, g1wb, g2wb);
  k_qkv<<<256, 256, 0, stream>>>(x1, x2, x3, x4, WTb, bqkv, Qg, Kg, Vg);
  k_attn<<<1024, 256, 0, stream>>>(Qg, Kg, Vg, Op, Lp);
  k_out<<<256, 256, 0, stream>>>(Op, Lp, owb, ob, g1wb, g1b, g2wb, g2b, SWb);
  k_final<<<5440, 256, 0, stream>>>(x1, x2, x3, x4, SWb, out);
}